// Round 1
// baseline (279.216 us; speedup 1.0000x reference)
//
#include <hip/hip_runtime.h>

// ---------------------------------------------------------------------------
// MaskedAutoregressiveFlow (RealNVP coupling) fused kernel for gfx950. R14.
// B=16384 rows, F=64, CTX=128, HID=512, L=8 layers, NB=2 hidden blocks.
//
// R14 = R13 (205us dispatch: split-half LDS b128 A-path, full fp8, D=4
//       B-pipeline) restructured from 64-row/1-block-per-CU to
//       32-row/2-blocks-per-CU.
// R13 counters: Occupancy 46% (LDS 95.7KB -> 1 block/CU), MfmaUtil 35%,
// HBM 1.9%. Arithmetic: MFMA floor ~163K cyc vs 492K measured -> 2/3 of
// time the matrix pipe idles at the ~40 per-block barriers. With 32-row
// blocks LDS drops to 47.9KB -> 2 independent blocks/CU (32 waves, HW cap);
// one block's barrier drain / coupling / permute overlaps the other's MFMA.
// Per-wave: 1 m-tile x 1 strip (single v16f acc) -> VGPR fits the 64-budget
// needed for 8 waves/SIMD (__launch_bounds__(1024, 8)).
// LDS h layout: addr(row,c) = row*528 + ((c>>3)&1)*256 + (c>>4)*8 + (c&7).
// Row stride 528B = 132 dwords = 4 mod 32 -> b128 reads of rows 0..31 tile
// all 32 banks (capacity-minimal 4-phase; SQ_LDS_BANK_CONFLICT counts these
// phases but they are full-BW, not waste).
// ---------------------------------------------------------------------------

typedef float v4f  __attribute__((ext_vector_type(4)));
typedef float v16f __attribute__((ext_vector_type(16)));
typedef unsigned char uchar;
typedef unsigned long long ull;

#define BATCH 16384
#define NF    64
#define NCTX  128
#define NL    8
#define ROWS  32     // rows per block (R14: was 64)

#define RS     528   // h row stride (bytes)
#define HHALF  256   // byte offset of k-odd 8-byte half groups
#define AST    176   // abuf row stride (bytes)
#define AHALF  80    // abuf half offset (K=160)
#define PST    68    // pbuf row stride (floats)

#define WSCALE     16.0f
#define WSCALE_INV 0.0625f

// packed-weight offsets (fp8 elements = bytes)
#define WIN_EPL   (160 * 512)
#define WH_EPB    (512 * 512)
#define WOUT_EPL  (512 * 64)
#define OFF_WIN   ((size_t)0)
#define OFF_WH    ((size_t)(8 * WIN_EPL))
#define OFF_WOUT  (OFF_WH + (size_t)(16 * WH_EPB))
#define TOT_PACK_ELEMS (OFF_WOUT + (size_t)(8 * WOUT_EPL))
#define NEED_WS   (TOT_PACK_ELEMS)

template<bool HI>
__device__ __forceinline__ unsigned int pk2(float a, float b, unsigned int old) {
    return __builtin_amdgcn_cvt_pk_fp8_f32(a, b, old, HI);
}
__device__ __forceinline__ uchar q8(float v) {
    return (uchar)(__builtin_amdgcn_cvt_pk_fp8_f32(v, v, 0u, false) & 0xffu);
}

// ---------------------------------------------------------------------------
// pack: fp32 -> fp8 e4m3 (x16), DESTINATION-ordered (one 8B store/thread).
// W_in/W_h -> 32x32x16 B-frag order: frag = kc*16 + nt;
//   lane l: k = kc*16 + (l>>5)*8 + j, n = nt*32 + (l&31).
// W_out -> 16x16x32 B-frag order: frag = kc*4 + nt;
//   lane l: k = kc*32 + (l>>4)*8 + j, n = nt*16 + (l&15).
// ---------------------------------------------------------------------------
__global__ void pack_weights_kernel(const float* __restrict__ W_in,
                                    const float* __restrict__ W_h,
                                    const float* __restrict__ W_out,
                                    unsigned char* __restrict__ ws) {
    const int TIN  = 8 * (WIN_EPL / 8);
    const int TH   = 16 * (WH_EPB / 8);
    const int TOUT = 8 * (WOUT_EPL / 8);
    int t = blockIdx.x * blockDim.x + threadIdx.x;
    if (t >= TIN + TH + TOUT) return;
    float v[8];
    if (t < TIN + TH) {
        const float* src; int r;
        if (t < TIN) {
            int i = t / (WIN_EPL / 8); r = t - i * (WIN_EPL / 8);
            src = W_in + (size_t)i * WIN_EPL;
        } else {
            int u = t - TIN; int ij = u >> 15; r = u & 32767;
            src = W_h + (size_t)ij * WH_EPB;
        }
        int frag = r >> 6, lane = r & 63;
        int k0 = (frag >> 4) * 16 + (lane >> 5) * 8;
        int n  = (frag & 15) * 32 + (lane & 31);
#pragma unroll
        for (int j = 0; j < 8; ++j)
            v[j] = src[(size_t)(k0 + j) * 512 + n] * WSCALE;
    } else {
        int u = t - TIN - TH;
        int i = u >> 12, r = u & 4095;
        const float* src = W_out + (size_t)i * WOUT_EPL;
        int frag = r >> 6, lane = r & 63;
        int k0 = (frag >> 2) * 32 + (lane >> 4) * 8;
        int n  = (frag & 3) * 16 + (lane & 15);
#pragma unroll
        for (int j = 0; j < 8; ++j)
            v[j] = src[(size_t)(k0 + j) * 64 + n] * WSCALE;
    }
    uint2 o;
    o.x = pk2<false>(v[0], v[1], 0u);
    o.x = pk2<true >(v[2], v[3], o.x);
    o.y = pk2<false>(v[4], v[5], 0u);
    o.y = pk2<true >(v[6], v[7], o.y);
    *(uint2*)(ws + (size_t)t * 8) = o;
}

__device__ __forceinline__ v16f mfma32(ull a, ull b, v16f c) {
    return __builtin_amdgcn_mfma_f32_32x32x16_fp8_fp8((long)a, (long)b, c, 0, 0, 0);
}
__device__ __forceinline__ v4f mfma16(ull a, ull b, v4f c) {
    return __builtin_amdgcn_mfma_f32_16x16x32_fp8_fp8((long)a, (long)b, c, 0, 0, 0);
}

// ---------------------------------------------------------------------------
// 32x32x16 fp8 stage, 32-row block, 16-wave config: wave owns 1 m-tile x
// 1 strip (=wave). A from split-half LDS via ds_read_b128 (2 kc per read);
// B from packed global with D=4 register pipeline (vmcnt>0 steady state).
// ---------------------------------------------------------------------------
template<int KC, bool PACKED>
__device__ __forceinline__ void gemm32(
    const uchar* __restrict__ wpk,
    const float* __restrict__ wraw,    // raw fp32 [K][512] fallback
    const float* __restrict__ bias,
    const uchar* __restrict__ Abuf, int ast, int ahalf,
    uchar* __restrict__ Obuf,
    int strip, int lane)
{
    constexpr int P = KC / 2;
    const int l31 = lane & 31, hl = lane >> 5;
    v16f acc;
#pragma unroll
    for (int r = 0; r < 16; ++r) acc[r] = 0.f;
    const uchar* a0p = Abuf + l31 * ast + hl * ahalf;   // rows 0..31
    const uchar* bptr =
        PACKED ? wpk + (size_t)(strip * 64 + lane) * 8 : (const uchar*)0;

    auto loadB = [&](int kc) -> ull {
        if (kc >= KC) kc = KC - 1;          // clamped dup, in-bounds
        if constexpr (PACKED) {
            return *(const ull*)(bptr + (size_t)kc * 8192);  // 16 strips x 512B
        } else {
            int n  = strip * 32 + l31;
            int k0 = kc * 16 + hl * 8;
            unsigned int lo, hi;
            lo = pk2<false>(wraw[(size_t)(k0 + 0) * 512 + n] * WSCALE,
                            wraw[(size_t)(k0 + 1) * 512 + n] * WSCALE, 0u);
            lo = pk2<true >(wraw[(size_t)(k0 + 2) * 512 + n] * WSCALE,
                            wraw[(size_t)(k0 + 3) * 512 + n] * WSCALE, lo);
            hi = pk2<false>(wraw[(size_t)(k0 + 4) * 512 + n] * WSCALE,
                            wraw[(size_t)(k0 + 5) * 512 + n] * WSCALE, 0u);
            hi = pk2<true >(wraw[(size_t)(k0 + 6) * 512 + n] * WSCALE,
                            wraw[(size_t)(k0 + 7) * 512 + n] * WSCALE, hi);
            return ((ull)hi << 32) | (ull)lo;
        }
    };

    ull b0 = loadB(0), b1 = loadB(1), b2 = loadB(2), b3 = loadB(3);
    int p2 = 0;
#pragma unroll 1
    for (; p2 + 1 < P; p2 += 2) {           // 4 kc per iteration
        ulonglong2 Aa = *(const ulonglong2*)(a0p + p2 * 16);
        acc = mfma32(Aa.x, b0, acc);
        b0 = loadB(2 * p2 + 4);
        acc = mfma32(Aa.y, b1, acc);
        b1 = loadB(2 * p2 + 5);
        ulonglong2 Ab = *(const ulonglong2*)(a0p + p2 * 16 + 16);
        acc = mfma32(Ab.x, b2, acc);
        b2 = loadB(2 * p2 + 6);
        acc = mfma32(Ab.y, b3, acc);
        b3 = loadB(2 * p2 + 7);
    }
    if constexpr (P & 1) {                  // last pair sits in b0,b1
        ulonglong2 Aa = *(const ulonglong2*)(a0p + (P - 1) * 16);
        acc = mfma32(Aa.x, b0, acc);
        acc = mfma32(Aa.y, b1, acc);
    }

    // epilogue: col n = strip*32+l31; row = (reg&3)+8*(reg>>2)+4*hl
    const int n = strip * 32 + l31;
    const int nb = ((n >> 3) & 1) * HHALF + ((n >> 4) << 3) + (n & 7);
    const float bv = bias[n];
#pragma unroll
    for (int reg = 0; reg < 16; ++reg) {
        int row = (reg & 3) + 8 * (reg >> 2) + 4 * hl;
        float v0 = fmaxf(fmaf(acc[reg], WSCALE_INV, bv), 0.f);
        Obuf[row * RS + nb] = q8(v0);
    }
}

// ---------------------------------------------------------------------------
// G3 (16x16x32 fp8), 32-row block: waves 0..7 active, mtb = wave>>2 (0..1),
// ntb = wave&3. A from split-half LDS (b64 per kc); D=4 B pipeline.
// fp32 out to pbuf.
// ---------------------------------------------------------------------------
template<bool PACKED>
__device__ __forceinline__ void gemm16_out(
    const uchar* __restrict__ wpk,
    const float* __restrict__ wraw,    // raw fp32 W_out [512][64]
    const float* __restrict__ bias,
    const uchar* __restrict__ Abuf,
    float* __restrict__ Pbuf,
    int mtb, int ntb, int lane)
{
    const int quad = lane >> 4, l15 = lane & 15;
    v4f acc; acc[0] = acc[1] = acc[2] = acc[3] = 0.f;
    const int row = mtb * 16 + l15;
    // c = kc*32 + quad*8 + j -> half = quad&1, pos = (kc*2 + (quad>>1))*8 + j
    const uchar* ap = Abuf + row * RS + (quad & 1) * HHALF + ((quad >> 1) << 3);
    const uchar* bptr =
        PACKED ? wpk + (size_t)(ntb * 64 + lane) * 8 : (const uchar*)0;
    constexpr int KC = 16;

    auto loadB = [&](int kc) -> ull {
        if (kc >= KC) kc = KC - 1;
        if constexpr (PACKED) {
            return *(const ull*)(bptr + (size_t)kc * 2048);   // 4 frags x 512B
        } else {
            int n  = ntb * 16 + l15;
            int k0 = kc * 32 + quad * 8;
            unsigned int lo, hi;
            lo = pk2<false>(wraw[(size_t)(k0 + 0) * 64 + n] * WSCALE,
                            wraw[(size_t)(k0 + 1) * 64 + n] * WSCALE, 0u);
            lo = pk2<true >(wraw[(size_t)(k0 + 2) * 64 + n] * WSCALE,
                            wraw[(size_t)(k0 + 3) * 64 + n] * WSCALE, lo);
            hi = pk2<false>(wraw[(size_t)(k0 + 4) * 64 + n] * WSCALE,
                            wraw[(size_t)(k0 + 5) * 64 + n] * WSCALE, 0u);
            hi = pk2<true >(wraw[(size_t)(k0 + 6) * 64 + n] * WSCALE,
                            wraw[(size_t)(k0 + 7) * 64 + n] * WSCALE, hi);
            return ((ull)hi << 32) | (ull)lo;
        }
    };
    auto step = [&](int kc, ull bb) {
        ull a = *(const ull*)(ap + kc * 16);
        acc = mfma16(a, bb, acc);
    };

    ull b0 = loadB(0), b1 = loadB(1), b2 = loadB(2), b3 = loadB(3);
    int kc = 0;
#pragma unroll 1
    for (; kc + 3 < KC; kc += 4) {
        step(kc + 0, b0); b0 = loadB(kc + 4);
        step(kc + 1, b1); b1 = loadB(kc + 5);
        step(kc + 2, b2); b2 = loadB(kc + 6);
        step(kc + 3, b3); b3 = loadB(kc + 7);
    }

    const int n = ntb * 16 + l15;
    const float bv = bias[n];
#pragma unroll
    for (int r = 0; r < 4; ++r)
        Pbuf[(mtb * 16 + quad * 4 + r) * PST + n] = fmaf(acc[r], WSCALE_INV, bv);
}

template<bool PACKED>
__global__ __launch_bounds__(1024, 8) void flow_kernel(
    const float* __restrict__ inputs,
    const float* __restrict__ ctx,
    const float* __restrict__ W_in,  const float* __restrict__ b_in,
    const float* __restrict__ W_h,   const float* __restrict__ b_h,
    const float* __restrict__ W_out, const float* __restrict__ b_out,
    const int*   __restrict__ perms,
    const uchar* __restrict__ wpk,
    float* __restrict__ out)
{
    __shared__ __align__(16) uchar hbuf0[ROWS * RS];   // 16,896 B
    __shared__ __align__(16) uchar hbuf1[ROWS * RS];   // 16,896 B
    __shared__ __align__(16) uchar abuf[ROWS * AST];   //  5,632 B
    __shared__ __align__(16) float xbuf[ROWS * NF];    //  8,192 B
    __shared__ int permsh[NF];                          // total 47,872 B

    float* pbuf    = (float*)hbuf1;   // p after G3 (G3 reads hbuf0)
    float* scratch = (float*)hbuf0;   // perm scratch (dead after G3)

    const int tid  = threadIdx.x;
    const int wave = tid >> 6;        // 0..15
    const int lane = tid & 63;
    const int trow = tid >> 4;        // 0..63 (guarded <ROWS where needed)
    const int tq   = tid & 15;        // 0..15
    const int tr2  = tid >> 5;        // 0..31
    const int tc2  = tid & 31;        // 0..31
    const int row0 = blockIdx.x * ROWS;

    // ---- load + clip x tile (1 float2 per thread: 1024 x 2 = 2048 floats)
    {
        float2 v = ((const float2*)(inputs + (size_t)row0 * NF))[tid];
        v.x = fminf(fmaxf(v.x, -1.f), 1.f);
        v.y = fminf(fmaxf(v.y, -1.f), 1.f);
        ((float2*)xbuf)[tid] = v;
    }
    // ---- stage ctx ONCE into abuf cols 32..159 (split-half layout)
    // thread (tr2, tc2): 4 cols starting at c0 = 32 + tc2*4 of row tr2
    {
        const float* crow = ctx + (size_t)(row0 + tr2) * NCTX + tc2 * 4;
        float4 f = *(const float4*)crow;
        unsigned int ck;
        ck = pk2<false>(f.x, f.y, 0u);
        ck = pk2<true >(f.z, f.w, ck);
        int c0 = 32 + tc2 * 4;
        // col c: half = (c>>3)&1, pos = (c>>4)*8 + (c&7); c0&7 in {0,4}
        *(unsigned int*)(abuf + tr2 * AST + ((c0 >> 3) & 1) * AHALF +
                         ((c0 >> 4) << 3) + (c0 & 7)) = ck;
    }
    float ld_acc = 0.f;
    __syncthreads();

#pragma unroll 1
    for (int i = 0; i < NL; ++i) {
        const int par = i & 1;
        const int idp = par ^ 1;

        // ---- stage id cols 0..31 into abuf (split-half); rows 0..31
        if (trow < ROWS && tq < 4) {
            const float* xr = xbuf + trow * NF + idp;
            uint2 idv;
            idv.x = pk2<false>(xr[2 * (tq * 8 + 0)], xr[2 * (tq * 8 + 1)], 0u);
            idv.x = pk2<true >(xr[2 * (tq * 8 + 2)], xr[2 * (tq * 8 + 3)], idv.x);
            idv.y = pk2<false>(xr[2 * (tq * 8 + 4)], xr[2 * (tq * 8 + 5)], 0u);
            idv.y = pk2<true >(xr[2 * (tq * 8 + 6)], xr[2 * (tq * 8 + 7)], idv.y);
            // col c = tq*8+j: half = tq&1, pos = (tq>>1)*8 + j
            *(uint2*)(abuf + trow * AST + (tq & 1) * AHALF + ((tq >> 1) << 3)) = idv;
        }
        __syncthreads();

        // ---- G0: K=160 (abuf -> hbuf0)
        gemm32<10, PACKED>(
            PACKED ? wpk + OFF_WIN + (size_t)i * WIN_EPL : (const uchar*)0,
            W_in + (size_t)i * WIN_EPL, b_in + i * 512,
            abuf, AST, AHALF, hbuf0, wave, lane);
        __syncthreads();
        // ---- G1 (hbuf0 -> hbuf1)
        gemm32<32, PACKED>(
            PACKED ? wpk + OFF_WH + (size_t)(i * 2 + 0) * WH_EPB : (const uchar*)0,
            W_h + (size_t)(i * 2 + 0) * WH_EPB, b_h + (i * 2 + 0) * 512,
            hbuf0, RS, HHALF, hbuf1, wave, lane);
        __syncthreads();
        // ---- G2 (hbuf1 -> hbuf0)
        gemm32<32, PACKED>(
            PACKED ? wpk + OFF_WH + (size_t)(i * 2 + 1) * WH_EPB : (const uchar*)0,
            W_h + (size_t)(i * 2 + 1) * WH_EPB, b_h + (i * 2 + 1) * 512,
            hbuf1, RS, HHALF, hbuf0, wave, lane);
        __syncthreads();
        // ---- G3: p = h @ W_out + b_out (hbuf0 -> pbuf = hbuf1); waves 0..7
        if (wave < 8)
            gemm16_out<PACKED>(
                PACKED ? wpk + OFF_WOUT + (size_t)i * WOUT_EPL : (const uchar*)0,
                W_out + (size_t)i * WOUT_EPL, b_out + i * 64,
                hbuf0, pbuf, wave >> 2, wave & 3, lane);
        __syncthreads();

        // ---- coupling: shift = p[:, :32]; scale = sigmoid(p[:,32:]+2)+1e-3
        if (trow < ROWS) {
#pragma unroll
            for (int j = 0; j < 2; ++j) {
                int sc = tq * 2 + j;
                float shiftv = pbuf[trow * PST + sc];
                float z = pbuf[trow * PST + 32 + sc] + 2.0f;
                float s = 1.0f / (1.0f + __expf(-z)) + 0.001f;
                int tc = 2 * sc + par;
                xbuf[trow * NF + tc] = xbuf[trow * NF + tc] * s + shiftv;
                ld_acc += __logf(s);
            }
        }
        __syncthreads();

        // ---- permutation: x = x[:, perm[i]]  (scratch = hbuf0, dead)
        if (i < NL - 1) {
            ((float2*)scratch)[tid] = ((float2*)xbuf)[tid];
            if (tid < NF) permsh[tid] = perms[i * NF + tid];
            __syncthreads();
#pragma unroll
            for (int j = 0; j < 2; ++j) {
                int c = tc2 * 2 + j;
                xbuf[tr2 * NF + c] = scratch[tr2 * NF + permsh[c]];
            }
            __syncthreads();
        }
    }

    // ---- outputs: clip(x) then logdet
    {
        float2 v = ((float2*)xbuf)[tid];
        v.x = fminf(fmaxf(v.x, -1.f), 1.f);
        v.y = fminf(fmaxf(v.y, -1.f), 1.f);
        ((float2*)(out + (size_t)row0 * NF))[tid] = v;
    }
    // reduce 16 partials per row (lanes 16r..16r+15 contiguous in a wave)
    ld_acc += __shfl_down(ld_acc, 1);
    ld_acc += __shfl_down(ld_acc, 2);
    ld_acc += __shfl_down(ld_acc, 4);
    ld_acc += __shfl_down(ld_acc, 8);
    if (tq == 0 && trow < ROWS)
        out[(size_t)BATCH * NF + row0 + trow] = ld_acc;
}

extern "C" void kernel_launch(void* const* d_in, const int* in_sizes, int n_in,
                              void* d_out, int out_size, void* d_ws, size_t ws_size,
                              hipStream_t stream) {
    const float* inputs  = (const float*)d_in[0];
    const float* context = (const float*)d_in[1];
    const float* W_in    = (const float*)d_in[2];
    const float* b_in    = (const float*)d_in[3];
    const float* W_h     = (const float*)d_in[4];
    const float* b_h     = (const float*)d_in[5];
    const float* W_out   = (const float*)d_in[6];
    const float* b_out   = (const float*)d_in[7];
    const int*   perms   = (const int*)d_in[8];
    float* out = (float*)d_out;

    const int nblocks = BATCH / ROWS;   // 512 -> 2 blocks per CU

    if (ws_size >= (size_t)NEED_WS) {
        uchar* ws = (uchar*)d_ws;
        const int total_threads = (int)(TOT_PACK_ELEMS / 8);    // 638976
        pack_weights_kernel<<<(total_threads + 255) / 256, 256, 0, stream>>>(
            W_in, W_h, W_out, ws);
        flow_kernel<true><<<nblocks, 1024, 0, stream>>>(
            inputs, context, W_in, b_in, W_h, b_h, W_out, b_out, perms, ws, out);
    } else {
        flow_kernel<false><<<nblocks, 1024, 0, stream>>>(
            inputs, context, W_in, b_in, W_h, b_h, W_out, b_out, perms,
            (const uchar*)0, out);
    }
}

// Round 2
// 213.501 us; speedup vs baseline: 1.3078x; 1.3078x over previous
//
#include <hip/hip_runtime.h>

// ---------------------------------------------------------------------------
// MaskedAutoregressiveFlow (RealNVP coupling) fused kernel for gfx950. R15.
// B=16384 rows, F=64, CTX=128, HID=512, L=8 layers, NB=2 hidden blocks.
//
// R15 = R13 geometry (64-row blocks, 256 blocks, 16 waves, 2 m-tiles/wave —
//       best measured, 205us dispatch) + MX-scaled MFMA for G0/G1/G2:
//       v_mfma_f32_32x32x64_f8f6f4 with scales=1.0 (E8M0 127) = plain fp8
//       GEMM at 2.14x the non-scaled rate (4686 vs 2190 TF measured).
// R14 post-mortem: 2 blocks/CU raised occupancy 46->75% but MfmaUtil FELL
// (35->32) and time rose 205->225us — occupancy was not the pacer. R13's
// MfmaUtil 35% == MFMA-pipe-busy 37% from first principles (9.19 cyc per
// 32x32x16 fp8 MFMA): the matrix pipe is the largest single term. MX halves
// it (17.2 cyc per K=64 vs 4x9.19), and halves MFMA + B-load issue counts.
// k-permutation trick: lane's 32B A-fragment read as 2x b128 from the
// split-half LDS layout yields k-order [0..7,16..23,8..15,24..31]; B is
// packed with the SAME permutation (dot products invariant), so no LDS
// layout change. W_in zero-padded K 160->192 on both A (abuf) and B (pack).
// LDS h layout: addr(row,c) = row*528 + ((c>>3)&1)*256 + (c>>4)*8 + (c&7).
// ---------------------------------------------------------------------------

typedef float v4f  __attribute__((ext_vector_type(4)));
typedef float v16f __attribute__((ext_vector_type(16)));
typedef int   v4i  __attribute__((ext_vector_type(4)));
typedef int   v8i  __attribute__((ext_vector_type(8)));
typedef unsigned char uchar;
typedef unsigned long long ull;

#define BATCH 16384
#define NF    64
#define NCTX  128
#define NL    8

#define RS     528   // h row stride (bytes)
#define HHALF  256   // byte offset of k-odd 8-byte half groups (hbuf)
#define AST    208   // abuf row stride (bytes), K padded to 192
#define AHALF  96    // abuf half offset (K=192)
#define PST    68    // pbuf row stride (floats)

#define WSCALE     16.0f
#define WSCALE_INV 0.0625f

// packed-weight offsets (fp8 elements = bytes). W_in K padded 160->192.
#define WIN_EPL   (192 * 512)
#define WH_EPB    (512 * 512)
#define WOUT_EPL  (512 * 64)
#define OFF_WIN   ((size_t)0)
#define OFF_WH    ((size_t)(8 * WIN_EPL))
#define OFF_WOUT  (OFF_WH + (size_t)(16 * WH_EPB))
#define TOT_PACK_ELEMS (OFF_WOUT + (size_t)(8 * WOUT_EPL))
#define NEED_WS   (TOT_PACK_ELEMS)

template<bool HI>
__device__ __forceinline__ unsigned int pk2(float a, float b, unsigned int old) {
    return __builtin_amdgcn_cvt_pk_fp8_f32(a, b, old, HI);
}
__device__ __forceinline__ uchar q8(float v) {
    return (uchar)(__builtin_amdgcn_cvt_pk_fp8_f32(v, v, 0u, false) & 0xffu);
}

// ---------------------------------------------------------------------------
// pack: fp32 -> fp8 e4m3 (x16), DESTINATION-ordered (one 8B store/thread).
// W_in/W_h -> MX 32x32x64 B-frag order with split-half k-permutation:
//   region kb (32768B) : slot s = strip*64+lane (32B) : group g (8B)
//   lane l: n = strip*32 + (l&31); byte (g*8+j) holds
//   k = kb*64 + (l>>5)*32 + pi[g]*8 + j, pi = {0,2,1,3}. Zero for k>=rawK.
// W_out -> 16x16x32 B-frag order (unchanged): frag = kc*4 + nt;
//   lane l: k = kc*32 + (l>>4)*8 + j, n = nt*16 + (l&15).
// ---------------------------------------------------------------------------
__global__ void pack_weights_kernel(const float* __restrict__ W_in,
                                    const float* __restrict__ W_h,
                                    const float* __restrict__ W_out,
                                    unsigned char* __restrict__ ws) {
    const int TIN  = 8 * (WIN_EPL / 8);    //  98304
    const int TH   = 16 * (WH_EPB / 8);    // 524288
    const int TOUT = 8 * (WOUT_EPL / 8);   //  32768
    int t = blockIdx.x * blockDim.x + threadIdx.x;
    if (t >= TIN + TH + TOUT) return;
    float v[8];
    if (t < TIN + TH) {
        const float* src; int r, rawK;
        if (t < TIN) {
            int i = t / (WIN_EPL / 8); r = t - i * (WIN_EPL / 8);
            src = W_in + (size_t)i * (160 * 512); rawK = 160;
        } else {
            int u = t - TIN; int ij = u >> 15; r = u & 32767;
            src = W_h + (size_t)ij * WH_EPB; rawK = 512;
        }
        int kb  = r >> 12, rem = r & 4095;
        int ls  = rem >> 2, g = rem & 3;
        int lane = ls & 63;
        int n = (ls >> 6) * 32 + (lane & 31);
        int pig = (g == 1) ? 2 : (g == 2) ? 1 : g;     // {0,2,1,3}
        int k0 = kb * 64 + (lane >> 5) * 32 + pig * 8;
#pragma unroll
        for (int j = 0; j < 8; ++j) {
            int k = k0 + j;
            v[j] = (k < rawK) ? src[(size_t)k * 512 + n] * WSCALE : 0.f;
        }
    } else {
        int u = t - TIN - TH;
        int i = u >> 12, r = u & 4095;
        const float* src = W_out + (size_t)i * WOUT_EPL;
        int frag = r >> 6, lane = r & 63;
        int k0 = (frag >> 2) * 32 + (lane >> 4) * 8;
        int n  = (frag & 3) * 16 + (lane & 15);
#pragma unroll
        for (int j = 0; j < 8; ++j)
            v[j] = src[(size_t)(k0 + j) * 64 + n] * WSCALE;
    }
    uint2 o;
    o.x = pk2<false>(v[0], v[1], 0u);
    o.x = pk2<true >(v[2], v[3], o.x);
    o.y = pk2<false>(v[4], v[5], 0u);
    o.y = pk2<true >(v[6], v[7], o.y);
    *(uint2*)(ws + (size_t)t * 8) = o;
}

__device__ __forceinline__ v16f mfma32(ull a, ull b, v16f c) {
    return __builtin_amdgcn_mfma_f32_32x32x16_fp8_fp8((long)a, (long)b, c, 0, 0, 0);
}
__device__ __forceinline__ v4f mfma16(ull a, ull b, v4f c) {
    return __builtin_amdgcn_mfma_f32_16x16x32_fp8_fp8((long)a, (long)b, c, 0, 0, 0);
}
// MX K=64, both operands fp8 e4m3 (cbsz=0, blgp=0), scale = 1.0 (E8M0 127).
__device__ __forceinline__ v16f mfma64(v8i a, v8i b, v16f c) {
    return __builtin_amdgcn_mfma_scale_f32_32x32x64_f8f6f4(
        a, b, c, 0, 0, 0, 0x7f7f7f7f, 0, 0x7f7f7f7f);
}

// ---------------------------------------------------------------------------
// MX 32x32x64 fp8 stage, 16-wave: wave owns 2 m-tiles x 1 strip (=wave).
// A: per K=64 block, 2x ds_read_b128 per m-tile from split-half LDS
//    (low region at +32kb+16hl, high at +half+32kb+16hl) -> lane k-order
//    [0..7,16..23,8..15,24..31] (matched by B packing).
// B: packed global, 2x b128 per kb, D=4 kb register pipeline.
// ---------------------------------------------------------------------------
template<int NKB>
__device__ __forceinline__ void gemm32mx(
    const uchar* __restrict__ wpk,
    const float* __restrict__ bias,
    const uchar* __restrict__ Abuf, int ast, int halfoff,
    uchar* __restrict__ Obuf,
    int strip, int lane)
{
    const int l31 = lane & 31, hl = lane >> 5;
    v16f acc0, acc1;
#pragma unroll
    for (int r = 0; r < 16; ++r) { acc0[r] = 0.f; acc1[r] = 0.f; }
    const uchar* aLo0 = Abuf + l31 * ast + hl * 16;   // rows 0..31, low region
    const uchar* aHi0 = aLo0 + halfoff;               // high region
    const uchar* aLo1 = aLo0 + 32 * ast;              // rows 32..63
    const uchar* aHi1 = aHi0 + 32 * ast;
    const uchar* bptr = wpk + (size_t)(strip * 64 + lane) * 32;

    auto loadB = [&](int kb) -> v8i {
        if (kb >= NKB) kb = NKB - 1;                  // clamped dup, in-bounds
        const uchar* p = bptr + (size_t)kb * 32768;   // 16 strips x 64 x 32B
        v4i lo = *(const v4i*)p;
        v4i hi = *(const v4i*)(p + 16);
        return __builtin_shufflevector(lo, hi, 0, 1, 2, 3, 4, 5, 6, 7);
    };
    auto loadA = [&](const uchar* lo_, const uchar* hi_, int kb) -> v8i {
        v4i lo = *(const v4i*)(lo_ + kb * 32);
        v4i hi = *(const v4i*)(hi_ + kb * 32);
        return __builtin_shufflevector(lo, hi, 0, 1, 2, 3, 4, 5, 6, 7);
    };

    v8i b0 = loadB(0), b1 = loadB(1), b2 = loadB(2), b3 = loadB(3);
#pragma unroll 1
    for (int kb = 0; kb + 3 < NKB; kb += 4) {
        acc0 = mfma64(loadA(aLo0, aHi0, kb + 0), b0, acc0);
        acc1 = mfma64(loadA(aLo1, aHi1, kb + 0), b0, acc1);
        b0 = loadB(kb + 4);
        acc0 = mfma64(loadA(aLo0, aHi0, kb + 1), b1, acc0);
        acc1 = mfma64(loadA(aLo1, aHi1, kb + 1), b1, acc1);
        b1 = loadB(kb + 5);
        acc0 = mfma64(loadA(aLo0, aHi0, kb + 2), b2, acc0);
        acc1 = mfma64(loadA(aLo1, aHi1, kb + 2), b2, acc1);
        b2 = loadB(kb + 6);
        acc0 = mfma64(loadA(aLo0, aHi0, kb + 3), b3, acc0);
        acc1 = mfma64(loadA(aLo1, aHi1, kb + 3), b3, acc1);
        b3 = loadB(kb + 7);
    }
    if constexpr ((NKB & 3) != 0) {
        constexpr int kb0 = NKB & ~3;
#pragma unroll
        for (int kb = kb0; kb < NKB; ++kb) {
            v8i bb = ((kb & 3) == 0) ? b0 : ((kb & 3) == 1) ? b1
                   : ((kb & 3) == 2) ? b2 : b3;
            acc0 = mfma64(loadA(aLo0, aHi0, kb), bb, acc0);
            acc1 = mfma64(loadA(aLo1, aHi1, kb), bb, acc1);
        }
    }

    // epilogue: col n = strip*32+l31; row = (reg&3)+8*(reg>>2)+4*hl (+32)
    const int n = strip * 32 + l31;
    const int nb = ((n >> 3) & 1) * HHALF + ((n >> 4) << 3) + (n & 7);
    const float bv = bias[n];
#pragma unroll
    for (int reg = 0; reg < 16; ++reg) {
        int row = (reg & 3) + 8 * (reg >> 2) + 4 * hl;
        float v0 = fmaxf(fmaf(acc0[reg], WSCALE_INV, bv), 0.f);
        Obuf[row * RS + nb] = q8(v0);
        float v1 = fmaxf(fmaf(acc1[reg], WSCALE_INV, bv), 0.f);
        Obuf[(row + 32) * RS + nb] = q8(v1);
    }
}

// ---------------------------------------------------------------------------
// Non-packed fallback: 32x32x16 fp8 stage (R13 path, pk on the fly).
// ---------------------------------------------------------------------------
template<int KC>
__device__ __forceinline__ void gemm32_raw(
    const float* __restrict__ wraw,    // raw fp32 [K][512]
    const float* __restrict__ bias,
    const uchar* __restrict__ Abuf, int ast, int ahalf,
    uchar* __restrict__ Obuf,
    int strip, int lane)
{
    constexpr int P = KC / 2;
    const int l31 = lane & 31, hl = lane >> 5;
    v16f acc0, acc1;
#pragma unroll
    for (int r = 0; r < 16; ++r) { acc0[r] = 0.f; acc1[r] = 0.f; }
    const uchar* a0p = Abuf + l31 * ast + hl * ahalf;   // rows 0..31
    const uchar* a1p = a0p + 32 * ast;                  // rows 32..63

    auto loadB = [&](int kc) -> ull {
        if (kc >= KC) kc = KC - 1;
        int n  = strip * 32 + l31;
        int k0 = kc * 16 + hl * 8;
        unsigned int lo, hi;
        lo = pk2<false>(wraw[(size_t)(k0 + 0) * 512 + n] * WSCALE,
                        wraw[(size_t)(k0 + 1) * 512 + n] * WSCALE, 0u);
        lo = pk2<true >(wraw[(size_t)(k0 + 2) * 512 + n] * WSCALE,
                        wraw[(size_t)(k0 + 3) * 512 + n] * WSCALE, lo);
        hi = pk2<false>(wraw[(size_t)(k0 + 4) * 512 + n] * WSCALE,
                        wraw[(size_t)(k0 + 5) * 512 + n] * WSCALE, 0u);
        hi = pk2<true >(wraw[(size_t)(k0 + 6) * 512 + n] * WSCALE,
                        wraw[(size_t)(k0 + 7) * 512 + n] * WSCALE, hi);
        return ((ull)hi << 32) | (ull)lo;
    };

    ull b0 = loadB(0), b1 = loadB(1), b2 = loadB(2), b3 = loadB(3);
    int p2 = 0;
#pragma unroll 1
    for (; p2 + 1 < P; p2 += 2) {
        ulonglong2 Aa0 = *(const ulonglong2*)(a0p + p2 * 16);
        ulonglong2 Aa1 = *(const ulonglong2*)(a1p + p2 * 16);
        acc0 = mfma32(Aa0.x, b0, acc0);
        acc1 = mfma32(Aa1.x, b0, acc1);
        b0 = loadB(2 * p2 + 4);
        acc0 = mfma32(Aa0.y, b1, acc0);
        acc1 = mfma32(Aa1.y, b1, acc1);
        b1 = loadB(2 * p2 + 5);
        ulonglong2 Ab0 = *(const ulonglong2*)(a0p + p2 * 16 + 16);
        ulonglong2 Ab1 = *(const ulonglong2*)(a1p + p2 * 16 + 16);
        acc0 = mfma32(Ab0.x, b2, acc0);
        acc1 = mfma32(Ab1.x, b2, acc1);
        b2 = loadB(2 * p2 + 6);
        acc0 = mfma32(Ab0.y, b3, acc0);
        acc1 = mfma32(Ab1.y, b3, acc1);
        b3 = loadB(2 * p2 + 7);
    }
    if constexpr (P & 1) {
        ulonglong2 Aa0 = *(const ulonglong2*)(a0p + (P - 1) * 16);
        ulonglong2 Aa1 = *(const ulonglong2*)(a1p + (P - 1) * 16);
        acc0 = mfma32(Aa0.x, b0, acc0);
        acc1 = mfma32(Aa1.x, b0, acc1);
        acc0 = mfma32(Aa0.y, b1, acc0);
        acc1 = mfma32(Aa1.y, b1, acc1);
    }

    const int n = strip * 32 + l31;
    const int nb = ((n >> 3) & 1) * HHALF + ((n >> 4) << 3) + (n & 7);
    const float bv = bias[n];
#pragma unroll
    for (int reg = 0; reg < 16; ++reg) {
        int row = (reg & 3) + 8 * (reg >> 2) + 4 * hl;
        float v0 = fmaxf(fmaf(acc0[reg], WSCALE_INV, bv), 0.f);
        Obuf[row * RS + nb] = q8(v0);
        float v1 = fmaxf(fmaf(acc1[reg], WSCALE_INV, bv), 0.f);
        Obuf[(row + 32) * RS + nb] = q8(v1);
    }
}

// ---------------------------------------------------------------------------
// G3 (16x16x32 fp8): mtb = wave>>2 (0..3), ntb = wave&3. A from split-half
// LDS (b64 per kc); D=4 B pipeline. fp32 out to pbuf.
// ---------------------------------------------------------------------------
template<bool PACKED>
__device__ __forceinline__ void gemm16_out(
    const uchar* __restrict__ wpk,
    const float* __restrict__ wraw,    // raw fp32 W_out [512][64]
    const float* __restrict__ bias,
    const uchar* __restrict__ Abuf,
    float* __restrict__ Pbuf,
    int mtb, int ntb, int lane)
{
    const int quad = lane >> 4, l15 = lane & 15;
    v4f acc; acc[0] = acc[1] = acc[2] = acc[3] = 0.f;
    const int row = mtb * 16 + l15;
    // c = kc*32 + quad*8 + j -> half = quad&1, pos = (kc*2 + (quad>>1))*8 + j
    const uchar* ap = Abuf + row * RS + (quad & 1) * HHALF + ((quad >> 1) << 3);
    const uchar* bptr =
        PACKED ? wpk + (size_t)(ntb * 64 + lane) * 8 : (const uchar*)0;
    constexpr int KC = 16;

    auto loadB = [&](int kc) -> ull {
        if (kc >= KC) kc = KC - 1;
        if constexpr (PACKED) {
            return *(const ull*)(bptr + (size_t)kc * 2048);   // 4 frags x 512B
        } else {
            int n  = ntb * 16 + l15;
            int k0 = kc * 32 + quad * 8;
            unsigned int lo, hi;
            lo = pk2<false>(wraw[(size_t)(k0 + 0) * 64 + n] * WSCALE,
                            wraw[(size_t)(k0 + 1) * 64 + n] * WSCALE, 0u);
            lo = pk2<true >(wraw[(size_t)(k0 + 2) * 64 + n] * WSCALE,
                            wraw[(size_t)(k0 + 3) * 64 + n] * WSCALE, lo);
            hi = pk2<false>(wraw[(size_t)(k0 + 4) * 64 + n] * WSCALE,
                            wraw[(size_t)(k0 + 5) * 64 + n] * WSCALE, 0u);
            hi = pk2<true >(wraw[(size_t)(k0 + 6) * 64 + n] * WSCALE,
                            wraw[(size_t)(k0 + 7) * 64 + n] * WSCALE, hi);
            return ((ull)hi << 32) | (ull)lo;
        }
    };
    auto step = [&](int kc, ull bb) {
        ull a = *(const ull*)(ap + kc * 16);
        acc = mfma16(a, bb, acc);
    };

    ull b0 = loadB(0), b1 = loadB(1), b2 = loadB(2), b3 = loadB(3);
    int kc = 0;
#pragma unroll 1
    for (; kc + 3 < KC; kc += 4) {
        step(kc + 0, b0); b0 = loadB(kc + 4);
        step(kc + 1, b1); b1 = loadB(kc + 5);
        step(kc + 2, b2); b2 = loadB(kc + 6);
        step(kc + 3, b3); b3 = loadB(kc + 7);
    }

    const int n = ntb * 16 + l15;
    const float bv = bias[n];
#pragma unroll
    for (int r = 0; r < 4; ++r)
        Pbuf[(mtb * 16 + quad * 4 + r) * PST + n] = fmaf(acc[r], WSCALE_INV, bv);
}

template<bool PACKED>
__global__ __launch_bounds__(1024, 4) void flow_kernel(
    const float* __restrict__ inputs,
    const float* __restrict__ ctx,
    const float* __restrict__ W_in,  const float* __restrict__ b_in,
    const float* __restrict__ W_h,   const float* __restrict__ b_h,
    const float* __restrict__ W_out, const float* __restrict__ b_out,
    const int*   __restrict__ perms,
    const uchar* __restrict__ wpk,
    float* __restrict__ out)
{
    __shared__ __align__(16) uchar hbuf0[64 * RS];   // 33,792 B
    __shared__ __align__(16) uchar hbuf1[64 * RS];   // 33,792 B
    __shared__ __align__(16) uchar abuf[64 * AST];   // 13,312 B
    __shared__ __align__(16) float xbuf[64 * NF];    // 16,384 B
    __shared__ int permsh[NF];                        // total 97,536 B

    float* pbuf    = (float*)hbuf1;   // p after G3 (G3 reads hbuf0)
    float* scratch = (float*)hbuf0;   // perm scratch (dead after G3)

    const int tid  = threadIdx.x;
    const int wave = tid >> 6;        // 0..15
    const int lane = tid & 63;
    const int trow = tid >> 4;        // 0..63
    const int tq   = tid & 15;        // 0..15
    const int row0 = blockIdx.x * 64;

    // ---- load + clip x tile (1 float4 per thread)
    {
        float4 v = ((const float4*)(inputs + (size_t)row0 * NF))[tid];
        v.x = fminf(fmaxf(v.x, -1.f), 1.f);
        v.y = fminf(fmaxf(v.y, -1.f), 1.f);
        v.z = fminf(fmaxf(v.z, -1.f), 1.f);
        v.w = fminf(fmaxf(v.w, -1.f), 1.f);
        ((float4*)xbuf)[tid] = v;
    }
    // ---- stage ctx ONCE into abuf cols 32..159 (split-half layout)
    {
        const float* crow = ctx + (size_t)(row0 + trow) * NCTX + tq * 8;
        float4 f0 = ((const float4*)crow)[0];
        float4 f1 = ((const float4*)crow)[1];
        uint2 ck;
        ck.x = pk2<false>(f0.x, f0.y, 0u);
        ck.x = pk2<true >(f0.z, f0.w, ck.x);
        ck.y = pk2<false>(f1.x, f1.y, 0u);
        ck.y = pk2<true >(f1.z, f1.w, ck.y);
        // col c = 32+tq*8+j: half = tq&1, pos = (2+(tq>>1))*8 + j
        *(uint2*)(abuf + trow * AST + (tq & 1) * AHALF + (2 + (tq >> 1)) * 8) = ck;
    }
    // ---- zero-pad abuf cols 160..191 ONCE (A-side of the K=192 pad)
    if (tid < 256) {
        int r = tid >> 2, q = tid & 3;
        *(ull*)(abuf + r * AST + (q & 1) * AHALF + 80 + ((q >> 1) << 3)) = 0ULL;
    }
    float ld_acc = 0.f;
    __syncthreads();

#pragma unroll 1
    for (int i = 0; i < NL; ++i) {
        const int par = i & 1;
        const int idp = par ^ 1;

        // ---- stage id cols 0..31 into abuf (split-half)
        if (tq < 4) {
            const float* xr = xbuf + trow * NF + idp;
            uint2 idv;
            idv.x = pk2<false>(xr[2 * (tq * 8 + 0)], xr[2 * (tq * 8 + 1)], 0u);
            idv.x = pk2<true >(xr[2 * (tq * 8 + 2)], xr[2 * (tq * 8 + 3)], idv.x);
            idv.y = pk2<false>(xr[2 * (tq * 8 + 4)], xr[2 * (tq * 8 + 5)], 0u);
            idv.y = pk2<true >(xr[2 * (tq * 8 + 6)], xr[2 * (tq * 8 + 7)], idv.y);
            // col c = tq*8+j: half = tq&1, pos = (tq>>1)*8 + j
            *(uint2*)(abuf + trow * AST + (tq & 1) * AHALF + ((tq >> 1) << 3)) = idv;
        }
        __syncthreads();

        if constexpr (PACKED) {
            // ---- G0: K=192 (padded), 3 K-blocks (abuf -> hbuf0)
            gemm32mx<3>(wpk + OFF_WIN + (size_t)i * WIN_EPL, b_in + i * 512,
                        abuf, AST, AHALF, hbuf0, wave, lane);
            __syncthreads();
            // ---- G1 (hbuf0 -> hbuf1), 8 K-blocks
            gemm32mx<8>(wpk + OFF_WH + (size_t)(i * 2 + 0) * WH_EPB,
                        b_h + (i * 2 + 0) * 512,
                        hbuf0, RS, HHALF, hbuf1, wave, lane);
            __syncthreads();
            // ---- G2 (hbuf1 -> hbuf0)
            gemm32mx<8>(wpk + OFF_WH + (size_t)(i * 2 + 1) * WH_EPB,
                        b_h + (i * 2 + 1) * 512,
                        hbuf1, RS, HHALF, hbuf0, wave, lane);
            __syncthreads();
        } else {
            gemm32_raw<10>(W_in + (size_t)i * (160 * 512), b_in + i * 512,
                           abuf, AST, AHALF, hbuf0, wave, lane);
            __syncthreads();
            gemm32_raw<32>(W_h + (size_t)(i * 2 + 0) * WH_EPB,
                           b_h + (i * 2 + 0) * 512,
                           hbuf0, RS, HHALF, hbuf1, wave, lane);
            __syncthreads();
            gemm32_raw<32>(W_h + (size_t)(i * 2 + 1) * WH_EPB,
                           b_h + (i * 2 + 1) * 512,
                           hbuf1, RS, HHALF, hbuf0, wave, lane);
            __syncthreads();
        }
        // ---- G3: p = h @ W_out + b_out (hbuf0 -> pbuf = hbuf1)
        gemm16_out<PACKED>(
            PACKED ? wpk + OFF_WOUT + (size_t)i * WOUT_EPL : (const uchar*)0,
            W_out + (size_t)i * WOUT_EPL, b_out + i * 64,
            hbuf0, pbuf, wave >> 2, wave & 3, lane);
        __syncthreads();

        // ---- coupling: shift = p[:, :32]; scale = sigmoid(p[:,32:]+2)+1e-3
        {
#pragma unroll
            for (int j = 0; j < 2; ++j) {
                int sc = tq * 2 + j;
                float shiftv = pbuf[trow * PST + sc];
                float z = pbuf[trow * PST + 32 + sc] + 2.0f;
                float s = 1.0f / (1.0f + __expf(-z)) + 0.001f;
                int tc = 2 * sc + par;
                xbuf[trow * NF + tc] = xbuf[trow * NF + tc] * s + shiftv;
                ld_acc += __logf(s);
            }
        }
        __syncthreads();

        // ---- permutation: x = x[:, perm[i]]  (scratch = hbuf0, dead)
        if (i < NL - 1) {
            ((float4*)scratch)[tid] = ((float4*)xbuf)[tid];
            if (tid < NF) permsh[tid] = perms[i * NF + tid];
            __syncthreads();
#pragma unroll
            for (int j = 0; j < 4; ++j) {
                int c = tq * 4 + j;
                xbuf[trow * NF + c] = scratch[trow * NF + permsh[c]];
            }
            __syncthreads();
        }
    }

    // ---- outputs: clip(x) then logdet
    {
        float4 v = ((float4*)xbuf)[tid];
        v.x = fminf(fmaxf(v.x, -1.f), 1.f);
        v.y = fminf(fmaxf(v.y, -1.f), 1.f);
        v.z = fminf(fmaxf(v.z, -1.f), 1.f);
        v.w = fminf(fmaxf(v.w, -1.f), 1.f);
        ((float4*)(out + (size_t)row0 * NF))[tid] = v;
    }
    // reduce 16 partials per row (lanes 16r..16r+15 contiguous in a wave)
    ld_acc += __shfl_down(ld_acc, 1);
    ld_acc += __shfl_down(ld_acc, 2);
    ld_acc += __shfl_down(ld_acc, 4);
    ld_acc += __shfl_down(ld_acc, 8);
    if (tq == 0) out[(size_t)BATCH * NF + row0 + trow] = ld_acc;
}

extern "C" void kernel_launch(void* const* d_in, const int* in_sizes, int n_in,
                              void* d_out, int out_size, void* d_ws, size_t ws_size,
                              hipStream_t stream) {
    const float* inputs  = (const float*)d_in[0];
    const float* context = (const float*)d_in[1];
    const float* W_in    = (const float*)d_in[2];
    const float* b_in    = (const float*)d_in[3];
    const float* W_h     = (const float*)d_in[4];
    const float* b_h     = (const float*)d_in[5];
    const float* W_out   = (const float*)d_in[6];
    const float* b_out   = (const float*)d_in[7];
    const int*   perms   = (const int*)d_in[8];
    float* out = (float*)d_out;

    if (ws_size >= (size_t)NEED_WS) {
        uchar* ws = (uchar*)d_ws;
        const int total_threads = (int)(TOT_PACK_ELEMS / 8);    // 655360
        pack_weights_kernel<<<(total_threads + 255) / 256, 256, 0, stream>>>(
            W_in, W_h, W_out, ws);
        flow_kernel<true><<<256, 1024, 0, stream>>>(
            inputs, context, W_in, b_in, W_h, b_h, W_out, b_out, perms, ws, out);
    } else {
        flow_kernel<false><<<256, 1024, 0, stream>>>(
            inputs, context, W_in, b_in, W_h, b_h, W_out, b_out, perms,
            (const uchar*)0, out);
    }
}

// Round 3
// 206.778 us; speedup vs baseline: 1.3503x; 1.0325x over previous
//
#include <hip/hip_runtime.h>

// ---------------------------------------------------------------------------
// MaskedAutoregressiveFlow (RealNVP coupling) fused kernel for gfx950. R16.
// B=16384 rows, F=64, CTX=128, HID=512, L=8 layers, NB=2 hidden blocks.
//
// R16 = R15 (142us dispatch: MX 32x32x64 fp8, 64-row blocks, 16 waves) +
//       TRANSPOSED MFMA epilogues (swap operands: C^T = W^T x act^T).
// R15 budget (341K cyc): MFMA 11.7K/layer (27%), A-LDS reads 14.6K/layer
// (pacer), epilogue ds_write_b8 storm ~6K/layer on the same LDS pipe,
// B-from-L2 ~4.7K/stage. Swapping MFMA operands is free (A/B fragment
// layouts are mutual transposes, scales=1.0 symmetric, same data, no pack
// change): lane then holds one batch row m=l31 with 4 consecutive n per
// acc-reg-quad -> 2x cvt_pk_fp8 -> ONE ds_write_b32 (vs 4x ds_write_b8).
// 32 b8 -> 8 b32 writes/thread/stage; G3 emits one float4 pbuf store.
// Bit-identical math (same products, same k order) -> absmax unchanged.
// C^T mapping (m101/m89, dtype-independent): 32x32: m = lane&31,
// n = (reg&3)+8*(reg>>2)+4*(lane>>5); 16x16: m = lane&15, n = quad*4+reg.
// LDS h layout: addr(row,c) = row*528 + ((c>>3)&1)*256 + (c>>4)*8 + (c&7).
// ---------------------------------------------------------------------------

typedef float v4f  __attribute__((ext_vector_type(4)));
typedef float v16f __attribute__((ext_vector_type(16)));
typedef int   v4i  __attribute__((ext_vector_type(4)));
typedef int   v8i  __attribute__((ext_vector_type(8)));
typedef unsigned char uchar;
typedef unsigned long long ull;

#define BATCH 16384
#define NF    64
#define NCTX  128
#define NL    8

#define RS     528   // h row stride (bytes)
#define HHALF  256   // byte offset of k-odd 8-byte half groups (hbuf)
#define AST    208   // abuf row stride (bytes), K padded to 192
#define AHALF  96    // abuf half offset (K=192)
#define PST    68    // pbuf row stride (floats)

#define WSCALE     16.0f
#define WSCALE_INV 0.0625f

// packed-weight offsets (fp8 elements = bytes). W_in K padded 160->192.
#define WIN_EPL   (192 * 512)
#define WH_EPB    (512 * 512)
#define WOUT_EPL  (512 * 64)
#define OFF_WIN   ((size_t)0)
#define OFF_WH    ((size_t)(8 * WIN_EPL))
#define OFF_WOUT  (OFF_WH + (size_t)(16 * WH_EPB))
#define TOT_PACK_ELEMS (OFF_WOUT + (size_t)(8 * WOUT_EPL))
#define NEED_WS   (TOT_PACK_ELEMS)

template<bool HI>
__device__ __forceinline__ unsigned int pk2(float a, float b, unsigned int old) {
    return __builtin_amdgcn_cvt_pk_fp8_f32(a, b, old, HI);
}
__device__ __forceinline__ uchar q8(float v) {
    return (uchar)(__builtin_amdgcn_cvt_pk_fp8_f32(v, v, 0u, false) & 0xffu);
}

// ---------------------------------------------------------------------------
// pack: fp32 -> fp8 e4m3 (x16), DESTINATION-ordered (one 8B store/thread).
// W_in/W_h -> MX 32x32x64 weight-frag order with split-half k-permutation:
//   region kb (32768B) : slot s = strip*64+lane (32B) : group g (8B)
//   lane l: n = strip*32 + (l&31); byte (g*8+j) holds
//   k = kb*64 + (l>>5)*32 + pi[g]*8 + j, pi = {0,2,1,3}. Zero for k>=rawK.
// W_out -> 16x16x32 weight-frag order: frag = kc*4 + nt;
//   lane l: k = kc*32 + (l>>4)*8 + j, n = nt*16 + (l&15).
// (Used as the SRC0/A operand of the swapped MFMA; fragment data identical
//  to the previous B-operand use — layouts are mutual transposes.)
// ---------------------------------------------------------------------------
__global__ void pack_weights_kernel(const float* __restrict__ W_in,
                                    const float* __restrict__ W_h,
                                    const float* __restrict__ W_out,
                                    unsigned char* __restrict__ ws) {
    const int TIN  = 8 * (WIN_EPL / 8);    //  98304
    const int TH   = 16 * (WH_EPB / 8);    // 524288
    const int TOUT = 8 * (WOUT_EPL / 8);   //  32768
    int t = blockIdx.x * blockDim.x + threadIdx.x;
    if (t >= TIN + TH + TOUT) return;
    float v[8];
    if (t < TIN + TH) {
        const float* src; int r, rawK;
        if (t < TIN) {
            int i = t / (WIN_EPL / 8); r = t - i * (WIN_EPL / 8);
            src = W_in + (size_t)i * (160 * 512); rawK = 160;
        } else {
            int u = t - TIN; int ij = u >> 15; r = u & 32767;
            src = W_h + (size_t)ij * WH_EPB; rawK = 512;
        }
        int kb  = r >> 12, rem = r & 4095;
        int ls  = rem >> 2, g = rem & 3;
        int lane = ls & 63;
        int n = (ls >> 6) * 32 + (lane & 31);
        int pig = (g == 1) ? 2 : (g == 2) ? 1 : g;     // {0,2,1,3}
        int k0 = kb * 64 + (lane >> 5) * 32 + pig * 8;
#pragma unroll
        for (int j = 0; j < 8; ++j) {
            int k = k0 + j;
            v[j] = (k < rawK) ? src[(size_t)k * 512 + n] * WSCALE : 0.f;
        }
    } else {
        int u = t - TIN - TH;
        int i = u >> 12, r = u & 4095;
        const float* src = W_out + (size_t)i * WOUT_EPL;
        int frag = r >> 6, lane = r & 63;
        int k0 = (frag >> 2) * 32 + (lane >> 4) * 8;
        int n  = (frag & 3) * 16 + (lane & 15);
#pragma unroll
        for (int j = 0; j < 8; ++j)
            v[j] = src[(size_t)(k0 + j) * 64 + n] * WSCALE;
    }
    uint2 o;
    o.x = pk2<false>(v[0], v[1], 0u);
    o.x = pk2<true >(v[2], v[3], o.x);
    o.y = pk2<false>(v[4], v[5], 0u);
    o.y = pk2<true >(v[6], v[7], o.y);
    *(uint2*)(ws + (size_t)t * 8) = o;
}

__device__ __forceinline__ v16f mfma32(ull a, ull b, v16f c) {
    return __builtin_amdgcn_mfma_f32_32x32x16_fp8_fp8((long)a, (long)b, c, 0, 0, 0);
}
__device__ __forceinline__ v4f mfma16(ull a, ull b, v4f c) {
    return __builtin_amdgcn_mfma_f32_16x16x32_fp8_fp8((long)a, (long)b, c, 0, 0, 0);
}
// MX K=64, both operands fp8 e4m3 (cbsz=0, blgp=0), scale = 1.0 (E8M0 127).
__device__ __forceinline__ v16f mfma64(v8i a, v8i b, v16f c) {
    return __builtin_amdgcn_mfma_scale_f32_32x32x64_f8f6f4(
        a, b, c, 0, 0, 0, 0x7f7f7f7f, 0, 0x7f7f7f7f);
}

// ---------------------------------------------------------------------------
// MX 32x32x64 fp8 stage, 16-wave: wave owns 2 m-tiles x 1 strip (=wave).
// SWAPPED operands: src0 = weight frag (global packed), src1 = act frag
// (split-half LDS, 2x ds_read_b128 per m-tile per kb) -> output C^T:
//   lane holds batch row m = lane&31 (acc0) / +32 (acc1);
//   regs 4q..4q+3 = cols n = strip*32 + q*8 + 4*(lane>>5) + {0..3}.
// Epilogue: 2x cvt_pk -> ONE ds_write_b32 per reg-quad (8 b32/thread).
// B (weights): D=4 kb register pipeline from packed global (L2-resident).
// ---------------------------------------------------------------------------
template<int NKB>
__device__ __forceinline__ void gemm32mx(
    const uchar* __restrict__ wpk,
    const float* __restrict__ bias,
    const uchar* __restrict__ Abuf, int ast, int halfoff,
    uchar* __restrict__ Obuf,
    int strip, int lane)
{
    const int l31 = lane & 31, hl = lane >> 5;
    v16f acc0, acc1;
#pragma unroll
    for (int r = 0; r < 16; ++r) { acc0[r] = 0.f; acc1[r] = 0.f; }
    const uchar* aLo0 = Abuf + l31 * ast + hl * 16;   // rows 0..31, low region
    const uchar* aHi0 = aLo0 + halfoff;               // high region
    const uchar* aLo1 = aLo0 + 32 * ast;              // rows 32..63
    const uchar* aHi1 = aHi0 + 32 * ast;
    const uchar* bptr = wpk + (size_t)(strip * 64 + lane) * 32;

    auto loadB = [&](int kb) -> v8i {
        if (kb >= NKB) kb = NKB - 1;                  // clamped dup, in-bounds
        const uchar* p = bptr + (size_t)kb * 32768;   // 16 strips x 64 x 32B
        v4i lo = *(const v4i*)p;
        v4i hi = *(const v4i*)(p + 16);
        return __builtin_shufflevector(lo, hi, 0, 1, 2, 3, 4, 5, 6, 7);
    };
    auto loadA = [&](const uchar* lo_, const uchar* hi_, int kb) -> v8i {
        v4i lo = *(const v4i*)(lo_ + kb * 32);
        v4i hi = *(const v4i*)(hi_ + kb * 32);
        return __builtin_shufflevector(lo, hi, 0, 1, 2, 3, 4, 5, 6, 7);
    };

    v8i b0 = loadB(0), b1 = loadB(1), b2 = loadB(2), b3 = loadB(3);
#pragma unroll 1
    for (int kb = 0; kb + 3 < NKB; kb += 4) {
        acc0 = mfma64(b0, loadA(aLo0, aHi0, kb + 0), acc0);
        acc1 = mfma64(b0, loadA(aLo1, aHi1, kb + 0), acc1);
        b0 = loadB(kb + 4);
        acc0 = mfma64(b1, loadA(aLo0, aHi0, kb + 1), acc0);
        acc1 = mfma64(b1, loadA(aLo1, aHi1, kb + 1), acc1);
        b1 = loadB(kb + 5);
        acc0 = mfma64(b2, loadA(aLo0, aHi0, kb + 2), acc0);
        acc1 = mfma64(b2, loadA(aLo1, aHi1, kb + 2), acc1);
        b2 = loadB(kb + 6);
        acc0 = mfma64(b3, loadA(aLo0, aHi0, kb + 3), acc0);
        acc1 = mfma64(b3, loadA(aLo1, aHi1, kb + 3), acc1);
        b3 = loadB(kb + 7);
    }
    if constexpr ((NKB & 3) != 0) {
        constexpr int kb0 = NKB & ~3;
#pragma unroll
        for (int kb = kb0; kb < NKB; ++kb) {
            v8i bb = ((kb & 3) == 0) ? b0 : ((kb & 3) == 1) ? b1
                   : ((kb & 3) == 2) ? b2 : b3;
            acc0 = mfma64(bb, loadA(aLo0, aHi0, kb), acc0);
            acc1 = mfma64(bb, loadA(aLo1, aHi1, kb), acc1);
        }
    }

    // epilogue (C^T): lane = batch row m = l31 / +32; reg-quad q covers
    // n = strip*32 + q*8 + 4*hl + {0..3} -> one aligned b32 per quad.
    const uchar* ob0c = Obuf + l31 * RS + 4 * hl;
    const uchar* ob1c = ob0c + 32 * RS;
#pragma unroll
    for (int q = 0; q < 4; ++q) {
        float4 bv = *(const float4*)(bias + strip * 32 + q * 8 + 4 * hl);
        unsigned int u0, u1;
        u0 = pk2<false>(fmaxf(fmaf(acc0[4 * q + 0], WSCALE_INV, bv.x), 0.f),
                        fmaxf(fmaf(acc0[4 * q + 1], WSCALE_INV, bv.y), 0.f), 0u);
        u0 = pk2<true >(fmaxf(fmaf(acc0[4 * q + 2], WSCALE_INV, bv.z), 0.f),
                        fmaxf(fmaf(acc0[4 * q + 3], WSCALE_INV, bv.w), 0.f), u0);
        u1 = pk2<false>(fmaxf(fmaf(acc1[4 * q + 0], WSCALE_INV, bv.x), 0.f),
                        fmaxf(fmaf(acc1[4 * q + 1], WSCALE_INV, bv.y), 0.f), 0u);
        u1 = pk2<true >(fmaxf(fmaf(acc1[4 * q + 2], WSCALE_INV, bv.z), 0.f),
                        fmaxf(fmaf(acc1[4 * q + 3], WSCALE_INV, bv.w), 0.f), u1);
        const int g = strip * 4 + q;                 // 8-col group index
        const int off = (g & 1) * HHALF + ((g >> 1) << 3);
        *(unsigned int*)(ob0c + off) = u0;
        *(unsigned int*)(ob1c + off) = u1;
    }
}

// ---------------------------------------------------------------------------
// Non-packed fallback: 32x32x16 fp8 stage (R13 path, pk on the fly,
// original operand order + byte epilogue — correctness path only).
// ---------------------------------------------------------------------------
template<int KC>
__device__ __forceinline__ void gemm32_raw(
    const float* __restrict__ wraw,    // raw fp32 [K][512]
    const float* __restrict__ bias,
    const uchar* __restrict__ Abuf, int ast, int ahalf,
    uchar* __restrict__ Obuf,
    int strip, int lane)
{
    constexpr int P = KC / 2;
    const int l31 = lane & 31, hl = lane >> 5;
    v16f acc0, acc1;
#pragma unroll
    for (int r = 0; r < 16; ++r) { acc0[r] = 0.f; acc1[r] = 0.f; }
    const uchar* a0p = Abuf + l31 * ast + hl * ahalf;   // rows 0..31
    const uchar* a1p = a0p + 32 * ast;                  // rows 32..63

    auto loadB = [&](int kc) -> ull {
        if (kc >= KC) kc = KC - 1;
        int n  = strip * 32 + l31;
        int k0 = kc * 16 + hl * 8;
        unsigned int lo, hi;
        lo = pk2<false>(wraw[(size_t)(k0 + 0) * 512 + n] * WSCALE,
                        wraw[(size_t)(k0 + 1) * 512 + n] * WSCALE, 0u);
        lo = pk2<true >(wraw[(size_t)(k0 + 2) * 512 + n] * WSCALE,
                        wraw[(size_t)(k0 + 3) * 512 + n] * WSCALE, lo);
        hi = pk2<false>(wraw[(size_t)(k0 + 4) * 512 + n] * WSCALE,
                        wraw[(size_t)(k0 + 5) * 512 + n] * WSCALE, 0u);
        hi = pk2<true >(wraw[(size_t)(k0 + 6) * 512 + n] * WSCALE,
                        wraw[(size_t)(k0 + 7) * 512 + n] * WSCALE, hi);
        return ((ull)hi << 32) | (ull)lo;
    };

    ull b0 = loadB(0), b1 = loadB(1), b2 = loadB(2), b3 = loadB(3);
    int p2 = 0;
#pragma unroll 1
    for (; p2 + 1 < P; p2 += 2) {
        ulonglong2 Aa0 = *(const ulonglong2*)(a0p + p2 * 16);
        ulonglong2 Aa1 = *(const ulonglong2*)(a1p + p2 * 16);
        acc0 = mfma32(Aa0.x, b0, acc0);
        acc1 = mfma32(Aa1.x, b0, acc1);
        b0 = loadB(2 * p2 + 4);
        acc0 = mfma32(Aa0.y, b1, acc0);
        acc1 = mfma32(Aa1.y, b1, acc1);
        b1 = loadB(2 * p2 + 5);
        ulonglong2 Ab0 = *(const ulonglong2*)(a0p + p2 * 16 + 16);
        ulonglong2 Ab1 = *(const ulonglong2*)(a1p + p2 * 16 + 16);
        acc0 = mfma32(Ab0.x, b2, acc0);
        acc1 = mfma32(Ab1.x, b2, acc1);
        b2 = loadB(2 * p2 + 6);
        acc0 = mfma32(Ab0.y, b3, acc0);
        acc1 = mfma32(Ab1.y, b3, acc1);
        b3 = loadB(2 * p2 + 7);
    }
    if constexpr (P & 1) {
        ulonglong2 Aa0 = *(const ulonglong2*)(a0p + (P - 1) * 16);
        ulonglong2 Aa1 = *(const ulonglong2*)(a1p + (P - 1) * 16);
        acc0 = mfma32(Aa0.x, b0, acc0);
        acc1 = mfma32(Aa1.x, b0, acc1);
        acc0 = mfma32(Aa0.y, b1, acc0);
        acc1 = mfma32(Aa1.y, b1, acc1);
    }

    const int n = strip * 32 + l31;
    const int nb = ((n >> 3) & 1) * HHALF + ((n >> 4) << 3) + (n & 7);
    const float bv = bias[n];
#pragma unroll
    for (int reg = 0; reg < 16; ++reg) {
        int row = (reg & 3) + 8 * (reg >> 2) + 4 * hl;
        float v0 = fmaxf(fmaf(acc0[reg], WSCALE_INV, bv), 0.f);
        Obuf[row * RS + nb] = q8(v0);
        float v1 = fmaxf(fmaf(acc1[reg], WSCALE_INV, bv), 0.f);
        Obuf[(row + 32) * RS + nb] = q8(v1);
    }
}

// ---------------------------------------------------------------------------
// G3 (16x16x32 fp8), SWAPPED: src0 = W_out frag, src1 = act frag.
// C^T: lane = batch row m = mtb*16 + (lane&15); regs = 4 consecutive n
// at n = ntb*16 + quad*4. Epilogue: ONE float4 store to pbuf per thread.
// ---------------------------------------------------------------------------
template<bool PACKED>
__device__ __forceinline__ void gemm16_out(
    const uchar* __restrict__ wpk,
    const float* __restrict__ wraw,    // raw fp32 W_out [512][64]
    const float* __restrict__ bias,
    const uchar* __restrict__ Abuf,
    float* __restrict__ Pbuf,
    int mtb, int ntb, int lane)
{
    const int quad = lane >> 4, l15 = lane & 15;
    v4f acc; acc[0] = acc[1] = acc[2] = acc[3] = 0.f;
    const int row = mtb * 16 + l15;
    // c = kc*32 + quad*8 + j -> half = quad&1, pos = (kc*2 + (quad>>1))*8 + j
    const uchar* ap = Abuf + row * RS + (quad & 1) * HHALF + ((quad >> 1) << 3);
    const uchar* bptr =
        PACKED ? wpk + (size_t)(ntb * 64 + lane) * 8 : (const uchar*)0;
    constexpr int KC = 16;

    auto loadB = [&](int kc) -> ull {
        if (kc >= KC) kc = KC - 1;
        if constexpr (PACKED) {
            return *(const ull*)(bptr + (size_t)kc * 2048);   // 4 frags x 512B
        } else {
            int n  = ntb * 16 + l15;
            int k0 = kc * 32 + quad * 8;
            unsigned int lo, hi;
            lo = pk2<false>(wraw[(size_t)(k0 + 0) * 64 + n] * WSCALE,
                            wraw[(size_t)(k0 + 1) * 64 + n] * WSCALE, 0u);
            lo = pk2<true >(wraw[(size_t)(k0 + 2) * 64 + n] * WSCALE,
                            wraw[(size_t)(k0 + 3) * 64 + n] * WSCALE, lo);
            hi = pk2<false>(wraw[(size_t)(k0 + 4) * 64 + n] * WSCALE,
                            wraw[(size_t)(k0 + 5) * 64 + n] * WSCALE, 0u);
            hi = pk2<true >(wraw[(size_t)(k0 + 6) * 64 + n] * WSCALE,
                            wraw[(size_t)(k0 + 7) * 64 + n] * WSCALE, hi);
            return ((ull)hi << 32) | (ull)lo;
        }
    };
    auto step = [&](int kc, ull bb) {
        ull a = *(const ull*)(ap + kc * 16);
        acc = mfma16(bb, a, acc);          // swapped: weights = src0
    };

    ull b0 = loadB(0), b1 = loadB(1), b2 = loadB(2), b3 = loadB(3);
    int kc = 0;
#pragma unroll 1
    for (; kc + 3 < KC; kc += 4) {
        step(kc + 0, b0); b0 = loadB(kc + 4);
        step(kc + 1, b1); b1 = loadB(kc + 5);
        step(kc + 2, b2); b2 = loadB(kc + 6);
        step(kc + 3, b3); b3 = loadB(kc + 7);
    }

    // C^T epilogue: m = row (lane-held batch row), n = ntb*16 + quad*4 + r
    float4 bv = *(const float4*)(bias + ntb * 16 + quad * 4);
    float4 o;
    o.x = fmaf(acc[0], WSCALE_INV, bv.x);
    o.y = fmaf(acc[1], WSCALE_INV, bv.y);
    o.z = fmaf(acc[2], WSCALE_INV, bv.z);
    o.w = fmaf(acc[3], WSCALE_INV, bv.w);
    *(float4*)(Pbuf + row * PST + ntb * 16 + quad * 4) = o;
}

template<bool PACKED>
__global__ __launch_bounds__(1024, 4) void flow_kernel(
    const float* __restrict__ inputs,
    const float* __restrict__ ctx,
    const float* __restrict__ W_in,  const float* __restrict__ b_in,
    const float* __restrict__ W_h,   const float* __restrict__ b_h,
    const float* __restrict__ W_out, const float* __restrict__ b_out,
    const int*   __restrict__ perms,
    const uchar* __restrict__ wpk,
    float* __restrict__ out)
{
    __shared__ __align__(16) uchar hbuf0[64 * RS];   // 33,792 B
    __shared__ __align__(16) uchar hbuf1[64 * RS];   // 33,792 B
    __shared__ __align__(16) uchar abuf[64 * AST];   // 13,312 B
    __shared__ __align__(16) float xbuf[64 * NF];    // 16,384 B
    __shared__ int permsh[NF];                        // total 97,536 B

    float* pbuf    = (float*)hbuf1;   // p after G3 (G3 reads hbuf0)
    float* scratch = (float*)hbuf0;   // perm scratch (dead after G3)

    const int tid  = threadIdx.x;
    const int wave = tid >> 6;        // 0..15
    const int lane = tid & 63;
    const int trow = tid >> 4;        // 0..63
    const int tq   = tid & 15;        // 0..15
    const int row0 = blockIdx.x * 64;

    // ---- load + clip x tile (1 float4 per thread)
    {
        float4 v = ((const float4*)(inputs + (size_t)row0 * NF))[tid];
        v.x = fminf(fmaxf(v.x, -1.f), 1.f);
        v.y = fminf(fmaxf(v.y, -1.f), 1.f);
        v.z = fminf(fmaxf(v.z, -1.f), 1.f);
        v.w = fminf(fmaxf(v.w, -1.f), 1.f);
        ((float4*)xbuf)[tid] = v;
    }
    // ---- stage ctx ONCE into abuf cols 32..159 (split-half layout)
    {
        const float* crow = ctx + (size_t)(row0 + trow) * NCTX + tq * 8;
        float4 f0 = ((const float4*)crow)[0];
        float4 f1 = ((const float4*)crow)[1];
        uint2 ck;
        ck.x = pk2<false>(f0.x, f0.y, 0u);
        ck.x = pk2<true >(f0.z, f0.w, ck.x);
        ck.y = pk2<false>(f1.x, f1.y, 0u);
        ck.y = pk2<true >(f1.z, f1.w, ck.y);
        // col c = 32+tq*8+j: half = tq&1, pos = (2+(tq>>1))*8 + j
        *(uint2*)(abuf + trow * AST + (tq & 1) * AHALF + (2 + (tq >> 1)) * 8) = ck;
    }
    // ---- zero-pad abuf cols 160..191 ONCE (A-side of the K=192 pad)
    if (tid < 256) {
        int r = tid >> 2, q = tid & 3;
        *(ull*)(abuf + r * AST + (q & 1) * AHALF + 80 + ((q >> 1) << 3)) = 0ULL;
    }
    float ld_acc = 0.f;
    __syncthreads();

#pragma unroll 1
    for (int i = 0; i < NL; ++i) {
        const int par = i & 1;
        const int idp = par ^ 1;

        // ---- stage id cols 0..31 into abuf (split-half)
        if (tq < 4) {
            const float* xr = xbuf + trow * NF + idp;
            uint2 idv;
            idv.x = pk2<false>(xr[2 * (tq * 8 + 0)], xr[2 * (tq * 8 + 1)], 0u);
            idv.x = pk2<true >(xr[2 * (tq * 8 + 2)], xr[2 * (tq * 8 + 3)], idv.x);
            idv.y = pk2<false>(xr[2 * (tq * 8 + 4)], xr[2 * (tq * 8 + 5)], 0u);
            idv.y = pk2<true >(xr[2 * (tq * 8 + 6)], xr[2 * (tq * 8 + 7)], idv.y);
            // col c = tq*8+j: half = tq&1, pos = (tq>>1)*8 + j
            *(uint2*)(abuf + trow * AST + (tq & 1) * AHALF + ((tq >> 1) << 3)) = idv;
        }
        __syncthreads();

        if constexpr (PACKED) {
            // ---- G0: K=192 (padded), 3 K-blocks (abuf -> hbuf0)
            gemm32mx<3>(wpk + OFF_WIN + (size_t)i * WIN_EPL, b_in + i * 512,
                        abuf, AST, AHALF, hbuf0, wave, lane);
            __syncthreads();
            // ---- G1 (hbuf0 -> hbuf1), 8 K-blocks
            gemm32mx<8>(wpk + OFF_WH + (size_t)(i * 2 + 0) * WH_EPB,
                        b_h + (i * 2 + 0) * 512,
                        hbuf0, RS, HHALF, hbuf1, wave, lane);
            __syncthreads();
            // ---- G2 (hbuf1 -> hbuf0)
            gemm32mx<8>(wpk + OFF_WH + (size_t)(i * 2 + 1) * WH_EPB,
                        b_h + (i * 2 + 1) * 512,
                        hbuf1, RS, HHALF, hbuf0, wave, lane);
            __syncthreads();
        } else {
            gemm32_raw<10>(W_in + (size_t)i * (160 * 512), b_in + i * 512,
                           abuf, AST, AHALF, hbuf0, wave, lane);
            __syncthreads();
            gemm32_raw<32>(W_h + (size_t)(i * 2 + 0) * WH_EPB,
                           b_h + (i * 2 + 0) * 512,
                           hbuf0, RS, HHALF, hbuf1, wave, lane);
            __syncthreads();
            gemm32_raw<32>(W_h + (size_t)(i * 2 + 1) * WH_EPB,
                           b_h + (i * 2 + 1) * 512,
                           hbuf1, RS, HHALF, hbuf0, wave, lane);
            __syncthreads();
        }
        // ---- G3: p = h @ W_out + b_out (hbuf0 -> pbuf = hbuf1)
        gemm16_out<PACKED>(
            PACKED ? wpk + OFF_WOUT + (size_t)i * WOUT_EPL : (const uchar*)0,
            W_out + (size_t)i * WOUT_EPL, b_out + i * 64,
            hbuf0, pbuf, wave >> 2, wave & 3, lane);
        __syncthreads();

        // ---- coupling: shift = p[:, :32]; scale = sigmoid(p[:,32:]+2)+1e-3
        {
#pragma unroll
            for (int j = 0; j < 2; ++j) {
                int sc = tq * 2 + j;
                float shiftv = pbuf[trow * PST + sc];
                float z = pbuf[trow * PST + 32 + sc] + 2.0f;
                float s = 1.0f / (1.0f + __expf(-z)) + 0.001f;
                int tc = 2 * sc + par;
                xbuf[trow * NF + tc] = xbuf[trow * NF + tc] * s + shiftv;
                ld_acc += __logf(s);
            }
        }
        __syncthreads();

        // ---- permutation: x = x[:, perm[i]]  (scratch = hbuf0, dead)
        if (i < NL - 1) {
            ((float4*)scratch)[tid] = ((float4*)xbuf)[tid];
            if (tid < NF) permsh[tid] = perms[i * NF + tid];
            __syncthreads();
#pragma unroll
            for (int j = 0; j < 4; ++j) {
                int c = tq * 4 + j;
                xbuf[trow * NF + c] = scratch[trow * NF + permsh[c]];
            }
            __syncthreads();
        }
    }

    // ---- outputs: clip(x) then logdet
    {
        float4 v = ((float4*)xbuf)[tid];
        v.x = fminf(fmaxf(v.x, -1.f), 1.f);
        v.y = fminf(fmaxf(v.y, -1.f), 1.f);
        v.z = fminf(fmaxf(v.z, -1.f), 1.f);
        v.w = fminf(fmaxf(v.w, -1.f), 1.f);
        ((float4*)(out + (size_t)row0 * NF))[tid] = v;
    }
    // reduce 16 partials per row (lanes 16r..16r+15 contiguous in a wave)
    ld_acc += __shfl_down(ld_acc, 1);
    ld_acc += __shfl_down(ld_acc, 2);
    ld_acc += __shfl_down(ld_acc, 4);
    ld_acc += __shfl_down(ld_acc, 8);
    if (tq == 0) out[(size_t)BATCH * NF + row0 + trow] = ld_acc;
}

extern "C" void kernel_launch(void* const* d_in, const int* in_sizes, int n_in,
                              void* d_out, int out_size, void* d_ws, size_t ws_size,
                              hipStream_t stream) {
    const float* inputs  = (const float*)d_in[0];
    const float* context = (const float*)d_in[1];
    const float* W_in    = (const float*)d_in[2];
    const float* b_in    = (const float*)d_in[3];
    const float* W_h     = (const float*)d_in[4];
    const float* b_h     = (const float*)d_in[5];
    const float* W_out   = (const float*)d_in[6];
    const float* b_out   = (const float*)d_in[7];
    const int*   perms   = (const int*)d_in[8];
    float* out = (float*)d_out;

    if (ws_size >= (size_t)NEED_WS) {
        uchar* ws = (uchar*)d_ws;
        const int total_threads = (int)(TOT_PACK_ELEMS / 8);    // 655360
        pack_weights_kernel<<<(total_threads + 255) / 256, 256, 0, stream>>>(
            W_in, W_h, W_out, ws);
        flow_kernel<true><<<256, 1024, 0, stream>>>(
            inputs, context, W_in, b_in, W_h, b_h, W_out, b_out, perms, ws, out);
    } else {
        flow_kernel<false><<<256, 1024, 0, stream>>>(
            inputs, context, W_in, b_in, W_h, b_h, W_out, b_out, perms,
            (const uchar*)0, out);
    }
}

// Round 4
// 200.256 us; speedup vs baseline: 1.3943x; 1.0326x over previous
//
#include <hip/hip_runtime.h>

// ---------------------------------------------------------------------------
// MaskedAutoregressiveFlow (RealNVP coupling) fused kernel for gfx950. R17.
// B=16384 rows, F=64, CTX=128, HID=512, L=8 layers, NB=2 hidden blocks.
//
// R17 = R16 (133us dispatch: MX 32x32x64 fp8, transposed epilogues) with the
//       GEMM decomposition widened: 8 waves (512 thr), each wave owns
//       2 strips x 2 m-tiles (4 v16f accs) instead of 16 waves x (1 strip x
//       2 m-tiles).
// R16 budget (40K cyc/layer): MFMA 11.7K (29%), A-LDS reads 14.6K (pacer:
// every wave re-reads the whole 64-row A tile), VALU 12.8K, B-L2 ~13K —
// pipes phase-locked (sum ~97%). Widening halves A-LDS traffic (each
// ds_read_b128 now feeds 2 MFMAs; per-kb 4 reads : 4 MFMAs) while keeping
// B read exactly once per CU (strip ownership stays unique — avoids R14's
// B-doubling regression). 2 waves/SIMD: D=2 B-prefetch (~280cyc) covers L2
// latency; 4 independent acc chains give ILP. Math identical -> absmax same.
// C^T mapping (m101, dtype-indep): 32x32: m = lane&31,
// n = (reg&3)+8*(reg>>2)+4*(lane>>5); 16x16: m = lane&15, n = quad*4+reg.
// LDS h layout: addr(row,c) = row*528 + ((c>>3)&1)*256 + (c>>4)*8 + (c&7).
// ---------------------------------------------------------------------------

typedef float v4f  __attribute__((ext_vector_type(4)));
typedef float v16f __attribute__((ext_vector_type(16)));
typedef int   v4i  __attribute__((ext_vector_type(4)));
typedef int   v8i  __attribute__((ext_vector_type(8)));
typedef unsigned char uchar;
typedef unsigned long long ull;

#define BATCH 16384
#define NF    64
#define NCTX  128
#define NL    8

#define RS     528   // h row stride (bytes)
#define HHALF  256   // byte offset of k-odd 8-byte half groups (hbuf)
#define AST    208   // abuf row stride (bytes), K padded to 192
#define AHALF  96    // abuf half offset (K=192)
#define PST    68    // pbuf row stride (floats)

#define WSCALE     16.0f
#define WSCALE_INV 0.0625f

// packed-weight offsets (fp8 elements = bytes). W_in K padded 160->192.
#define WIN_EPL   (192 * 512)
#define WH_EPB    (512 * 512)
#define WOUT_EPL  (512 * 64)
#define OFF_WIN   ((size_t)0)
#define OFF_WH    ((size_t)(8 * WIN_EPL))
#define OFF_WOUT  (OFF_WH + (size_t)(16 * WH_EPB))
#define TOT_PACK_ELEMS (OFF_WOUT + (size_t)(8 * WOUT_EPL))
#define NEED_WS   (TOT_PACK_ELEMS)

template<bool HI>
__device__ __forceinline__ unsigned int pk2(float a, float b, unsigned int old) {
    return __builtin_amdgcn_cvt_pk_fp8_f32(a, b, old, HI);
}
__device__ __forceinline__ uchar q8(float v) {
    return (uchar)(__builtin_amdgcn_cvt_pk_fp8_f32(v, v, 0u, false) & 0xffu);
}

// ---------------------------------------------------------------------------
// pack: fp32 -> fp8 e4m3 (x16), DESTINATION-ordered (one 8B store/thread).
// W_in/W_h -> MX 32x32x64 weight-frag order with split-half k-permutation:
//   region kb (32768B) : slot s = strip*64+lane (32B) : group g (8B)
//   lane l: n = strip*32 + (l&31); byte (g*8+j) holds
//   k = kb*64 + (l>>5)*32 + pi[g]*8 + j, pi = {0,2,1,3}. Zero for k>=rawK.
// W_out -> 16x16x32 weight-frag order: frag = kc*4 + nt;
//   lane l: k = kc*32 + (l>>4)*8 + j, n = nt*16 + (l&15).
// ---------------------------------------------------------------------------
__global__ void pack_weights_kernel(const float* __restrict__ W_in,
                                    const float* __restrict__ W_h,
                                    const float* __restrict__ W_out,
                                    unsigned char* __restrict__ ws) {
    const int TIN  = 8 * (WIN_EPL / 8);    //  98304
    const int TH   = 16 * (WH_EPB / 8);    // 524288
    const int TOUT = 8 * (WOUT_EPL / 8);   //  32768
    int t = blockIdx.x * blockDim.x + threadIdx.x;
    if (t >= TIN + TH + TOUT) return;
    float v[8];
    if (t < TIN + TH) {
        const float* src; int r, rawK;
        if (t < TIN) {
            int i = t / (WIN_EPL / 8); r = t - i * (WIN_EPL / 8);
            src = W_in + (size_t)i * (160 * 512); rawK = 160;
        } else {
            int u = t - TIN; int ij = u >> 15; r = u & 32767;
            src = W_h + (size_t)ij * WH_EPB; rawK = 512;
        }
        int kb  = r >> 12, rem = r & 4095;
        int ls  = rem >> 2, g = rem & 3;
        int lane = ls & 63;
        int n = (ls >> 6) * 32 + (lane & 31);
        int pig = (g == 1) ? 2 : (g == 2) ? 1 : g;     // {0,2,1,3}
        int k0 = kb * 64 + (lane >> 5) * 32 + pig * 8;
#pragma unroll
        for (int j = 0; j < 8; ++j) {
            int k = k0 + j;
            v[j] = (k < rawK) ? src[(size_t)k * 512 + n] * WSCALE : 0.f;
        }
    } else {
        int u = t - TIN - TH;
        int i = u >> 12, r = u & 4095;
        const float* src = W_out + (size_t)i * WOUT_EPL;
        int frag = r >> 6, lane = r & 63;
        int k0 = (frag >> 2) * 32 + (lane >> 4) * 8;
        int n  = (frag & 3) * 16 + (lane & 15);
#pragma unroll
        for (int j = 0; j < 8; ++j)
            v[j] = src[(size_t)(k0 + j) * 64 + n] * WSCALE;
    }
    uint2 o;
    o.x = pk2<false>(v[0], v[1], 0u);
    o.x = pk2<true >(v[2], v[3], o.x);
    o.y = pk2<false>(v[4], v[5], 0u);
    o.y = pk2<true >(v[6], v[7], o.y);
    *(uint2*)(ws + (size_t)t * 8) = o;
}

__device__ __forceinline__ v16f mfma32(ull a, ull b, v16f c) {
    return __builtin_amdgcn_mfma_f32_32x32x16_fp8_fp8((long)a, (long)b, c, 0, 0, 0);
}
__device__ __forceinline__ v4f mfma16(ull a, ull b, v4f c) {
    return __builtin_amdgcn_mfma_f32_16x16x32_fp8_fp8((long)a, (long)b, c, 0, 0, 0);
}
// MX K=64, both operands fp8 e4m3 (cbsz=0, blgp=0), scale = 1.0 (E8M0 127).
__device__ __forceinline__ v16f mfma64(v8i a, v8i b, v16f c) {
    return __builtin_amdgcn_mfma_scale_f32_32x32x64_f8f6f4(
        a, b, c, 0, 0, 0, 0x7f7f7f7f, 0, 0x7f7f7f7f);
}

// ---------------------------------------------------------------------------
// MX 32x32x64 fp8 stage, 8-wave: wave owns strips {2p, 2p+1} x both m-tiles
// (4 v16f accs). SWAPPED operands (src0 = weight frag, src1 = act frag).
// A: per kb, 2x ds_read_b128 per m-tile (split-half LDS) — each A fragment
//    feeds 2 MFMAs (both strips). Per-CU A-LDS traffic halved vs R16.
// B: per strip, D=2 kb register pipeline from packed global; each strip's
//    weights loaded by exactly ONE wave (B read once per CU).
// Epilogue (C^T): lane = batch row m = l31 (+32); per (strip, q): one b32.
// ---------------------------------------------------------------------------
template<int NKB>
__device__ __forceinline__ void gemm32mx(
    const uchar* __restrict__ wpk,
    const float* __restrict__ bias,
    const uchar* __restrict__ Abuf, int ast, int halfoff,
    uchar* __restrict__ Obuf,
    int pair, int lane)
{
    const int l31 = lane & 31, hl = lane >> 5;
    v16f a00, a01, a10, a11;          // acc[strip][mhalf]
#pragma unroll
    for (int r = 0; r < 16; ++r) { a00[r] = 0.f; a01[r] = 0.f;
                                   a10[r] = 0.f; a11[r] = 0.f; }
    const uchar* aLo0 = Abuf + l31 * ast + hl * 16;   // rows 0..31, low region
    const uchar* aHi0 = aLo0 + halfoff;               // high region
    const uchar* aLo1 = aLo0 + 32 * ast;              // rows 32..63
    const uchar* aHi1 = aHi0 + 32 * ast;
    const uchar* bp = wpk + (size_t)(pair * 128 + lane) * 32;  // strip 2p base

    auto loadB = [&](int s, int kb) -> v8i {
        if (kb >= NKB) kb = NKB - 1;                  // clamped dup, in-bounds
        const uchar* p = bp + s * 2048 + (size_t)kb * 32768;
        v4i lo = *(const v4i*)p;
        v4i hi = *(const v4i*)(p + 16);
        return __builtin_shufflevector(lo, hi, 0, 1, 2, 3, 4, 5, 6, 7);
    };
    auto loadA = [&](const uchar* lo_, const uchar* hi_, int kb) -> v8i {
        v4i lo = *(const v4i*)(lo_ + kb * 32);
        v4i hi = *(const v4i*)(hi_ + kb * 32);
        return __builtin_shufflevector(lo, hi, 0, 1, 2, 3, 4, 5, 6, 7);
    };

    v8i b00 = loadB(0, 0), b10 = loadB(1, 0);         // strips, kb
    v8i b01 = loadB(0, 1), b11 = loadB(1, 1);         // strips, kb+1
    int kb = 0;
#pragma unroll 1
    for (; kb + 1 < NKB; kb += 2) {
        v8i x0 = loadA(aLo0, aHi0, kb);
        v8i x1 = loadA(aLo1, aHi1, kb);
        a00 = mfma64(b00, x0, a00);
        a01 = mfma64(b00, x1, a01);
        a10 = mfma64(b10, x0, a10);
        a11 = mfma64(b10, x1, a11);
        b00 = loadB(0, kb + 2); b10 = loadB(1, kb + 2);
        x0 = loadA(aLo0, aHi0, kb + 1);
        x1 = loadA(aLo1, aHi1, kb + 1);
        a00 = mfma64(b01, x0, a00);
        a01 = mfma64(b01, x1, a01);
        a10 = mfma64(b11, x0, a10);
        a11 = mfma64(b11, x1, a11);
        b01 = loadB(0, kb + 3); b11 = loadB(1, kb + 3);
    }
    if constexpr (NKB & 1) {                          // tail kb = NKB-1
        v8i x0 = loadA(aLo0, aHi0, NKB - 1);
        v8i x1 = loadA(aLo1, aHi1, NKB - 1);
        a00 = mfma64(b00, x0, a00);
        a01 = mfma64(b00, x1, a01);
        a10 = mfma64(b10, x0, a10);
        a11 = mfma64(b10, x1, a11);
    }

    // epilogue (C^T): lane = batch row m = l31 (mhalf0) / l31+32 (mhalf1);
    // reg-quad q of strip s covers n = s*32 + q*8 + 4*hl + {0..3}.
    const uchar* ob0 = Obuf + l31 * RS + 4 * hl;      // mhalf 0
    const uchar* ob1 = ob0 + 32 * RS;                 // mhalf 1
    auto emit = [&](const v16f& am0, const v16f& am1, int strip) {
#pragma unroll
        for (int q = 0; q < 4; ++q) {
            const int n0 = strip * 32 + q * 8 + 4 * hl;
            float4 bv = *(const float4*)(bias + n0);
            unsigned int u0, u1;
            u0 = pk2<false>(fmaxf(fmaf(am0[4 * q + 0], WSCALE_INV, bv.x), 0.f),
                            fmaxf(fmaf(am0[4 * q + 1], WSCALE_INV, bv.y), 0.f), 0u);
            u0 = pk2<true >(fmaxf(fmaf(am0[4 * q + 2], WSCALE_INV, bv.z), 0.f),
                            fmaxf(fmaf(am0[4 * q + 3], WSCALE_INV, bv.w), 0.f), u0);
            u1 = pk2<false>(fmaxf(fmaf(am1[4 * q + 0], WSCALE_INV, bv.x), 0.f),
                            fmaxf(fmaf(am1[4 * q + 1], WSCALE_INV, bv.y), 0.f), 0u);
            u1 = pk2<true >(fmaxf(fmaf(am1[4 * q + 2], WSCALE_INV, bv.z), 0.f),
                            fmaxf(fmaf(am1[4 * q + 3], WSCALE_INV, bv.w), 0.f), u1);
            const int g = strip * 4 + q;              // 8-col group index
            const int off = (g & 1) * HHALF + ((g >> 1) << 3);
            *(unsigned int*)(ob0 + off) = u0;
            *(unsigned int*)(ob1 + off) = u1;
        }
    };
    emit(a00, a01, pair * 2 + 0);
    emit(a10, a11, pair * 2 + 1);
}

// ---------------------------------------------------------------------------
// Non-packed fallback: 32x32x16 fp8 stage (R13 path, pk on the fly,
// original operand order + byte epilogue — correctness path only).
// One call = 2 m-tiles x 1 strip; caller invokes twice (strips 2p, 2p+1).
// ---------------------------------------------------------------------------
template<int KC>
__device__ __forceinline__ void gemm32_raw(
    const float* __restrict__ wraw,    // raw fp32 [K][512]
    const float* __restrict__ bias,
    const uchar* __restrict__ Abuf, int ast, int ahalf,
    uchar* __restrict__ Obuf,
    int strip, int lane)
{
    constexpr int P = KC / 2;
    const int l31 = lane & 31, hl = lane >> 5;
    v16f acc0, acc1;
#pragma unroll
    for (int r = 0; r < 16; ++r) { acc0[r] = 0.f; acc1[r] = 0.f; }
    const uchar* a0p = Abuf + l31 * ast + hl * ahalf;   // rows 0..31
    const uchar* a1p = a0p + 32 * ast;                  // rows 32..63

    auto loadB = [&](int kc) -> ull {
        if (kc >= KC) kc = KC - 1;
        int n  = strip * 32 + l31;
        int k0 = kc * 16 + hl * 8;
        unsigned int lo, hi;
        lo = pk2<false>(wraw[(size_t)(k0 + 0) * 512 + n] * WSCALE,
                        wraw[(size_t)(k0 + 1) * 512 + n] * WSCALE, 0u);
        lo = pk2<true >(wraw[(size_t)(k0 + 2) * 512 + n] * WSCALE,
                        wraw[(size_t)(k0 + 3) * 512 + n] * WSCALE, lo);
        hi = pk2<false>(wraw[(size_t)(k0 + 4) * 512 + n] * WSCALE,
                        wraw[(size_t)(k0 + 5) * 512 + n] * WSCALE, 0u);
        hi = pk2<true >(wraw[(size_t)(k0 + 6) * 512 + n] * WSCALE,
                        wraw[(size_t)(k0 + 7) * 512 + n] * WSCALE, hi);
        return ((ull)hi << 32) | (ull)lo;
    };

    ull b0 = loadB(0), b1 = loadB(1), b2 = loadB(2), b3 = loadB(3);
    int p2 = 0;
#pragma unroll 1
    for (; p2 + 1 < P; p2 += 2) {
        ulonglong2 Aa0 = *(const ulonglong2*)(a0p + p2 * 16);
        ulonglong2 Aa1 = *(const ulonglong2*)(a1p + p2 * 16);
        acc0 = mfma32(Aa0.x, b0, acc0);
        acc1 = mfma32(Aa1.x, b0, acc1);
        b0 = loadB(2 * p2 + 4);
        acc0 = mfma32(Aa0.y, b1, acc0);
        acc1 = mfma32(Aa1.y, b1, acc1);
        b1 = loadB(2 * p2 + 5);
        ulonglong2 Ab0 = *(const ulonglong2*)(a0p + p2 * 16 + 16);
        ulonglong2 Ab1 = *(const ulonglong2*)(a1p + p2 * 16 + 16);
        acc0 = mfma32(Ab0.x, b2, acc0);
        acc1 = mfma32(Ab1.x, b2, acc1);
        b2 = loadB(2 * p2 + 6);
        acc0 = mfma32(Ab0.y, b3, acc0);
        acc1 = mfma32(Ab1.y, b3, acc1);
        b3 = loadB(2 * p2 + 7);
    }
    if constexpr (P & 1) {
        ulonglong2 Aa0 = *(const ulonglong2*)(a0p + (P - 1) * 16);
        ulonglong2 Aa1 = *(const ulonglong2*)(a1p + (P - 1) * 16);
        acc0 = mfma32(Aa0.x, b0, acc0);
        acc1 = mfma32(Aa1.x, b0, acc1);
        acc0 = mfma32(Aa0.y, b1, acc0);
        acc1 = mfma32(Aa1.y, b1, acc1);
    }

    const int n = strip * 32 + l31;
    const int nb = ((n >> 3) & 1) * HHALF + ((n >> 4) << 3) + (n & 7);
    const float bv = bias[n];
#pragma unroll
    for (int reg = 0; reg < 16; ++reg) {
        int row = (reg & 3) + 8 * (reg >> 2) + 4 * hl;
        float v0 = fmaxf(fmaf(acc0[reg], WSCALE_INV, bv), 0.f);
        Obuf[row * RS + nb] = q8(v0);
        float v1 = fmaxf(fmaf(acc1[reg], WSCALE_INV, bv), 0.f);
        Obuf[(row + 32) * RS + nb] = q8(v1);
    }
}

// ---------------------------------------------------------------------------
// G3 (16x16x32 fp8), 8-wave, SWAPPED: src0 = W_out frag, src1 = act frag.
// wave w: ntb = w&3, m-tiles {w>>2, (w>>2)+2}; shared B per wave.
// C^T: lane = batch row m = mtb*16 + (lane&15); regs = 4 consecutive n at
// n = ntb*16 + quad*4. Epilogue: ONE float4 store per (thread, m-tile).
// ---------------------------------------------------------------------------
template<bool PACKED>
__device__ __forceinline__ void gemm16_out(
    const uchar* __restrict__ wpk,
    const float* __restrict__ wraw,    // raw fp32 W_out [512][64]
    const float* __restrict__ bias,
    const uchar* __restrict__ Abuf,
    float* __restrict__ Pbuf,
    int w, int lane)
{
    const int quad = lane >> 4, l15 = lane & 15;
    const int ntb  = w & 3;
    const int mtb0 = w >> 2;           // 0..1
    const int row0 = mtb0 * 16 + l15;
    const int row1 = row0 + 32;        // mtb0 + 2
    v4f acc0, acc1;
    acc0[0] = acc0[1] = acc0[2] = acc0[3] = 0.f;
    acc1[0] = acc1[1] = acc1[2] = acc1[3] = 0.f;
    // c = kc*32 + quad*8 + j -> half = quad&1, pos = (kc*2 + (quad>>1))*8 + j
    const uchar* ap0 = Abuf + row0 * RS + (quad & 1) * HHALF + ((quad >> 1) << 3);
    const uchar* ap1 = Abuf + row1 * RS + (quad & 1) * HHALF + ((quad >> 1) << 3);
    const uchar* bptr =
        PACKED ? wpk + (size_t)(ntb * 64 + lane) * 8 : (const uchar*)0;
    constexpr int KC = 16;

    auto loadB = [&](int kc) -> ull {
        if (kc >= KC) kc = KC - 1;
        if constexpr (PACKED) {
            return *(const ull*)(bptr + (size_t)kc * 2048);   // 4 frags x 512B
        } else {
            int n  = ntb * 16 + l15;
            int k0 = kc * 32 + quad * 8;
            unsigned int lo, hi;
            lo = pk2<false>(wraw[(size_t)(k0 + 0) * 64 + n] * WSCALE,
                            wraw[(size_t)(k0 + 1) * 64 + n] * WSCALE, 0u);
            lo = pk2<true >(wraw[(size_t)(k0 + 2) * 64 + n] * WSCALE,
                            wraw[(size_t)(k0 + 3) * 64 + n] * WSCALE, lo);
            hi = pk2<false>(wraw[(size_t)(k0 + 4) * 64 + n] * WSCALE,
                            wraw[(size_t)(k0 + 5) * 64 + n] * WSCALE, 0u);
            hi = pk2<true >(wraw[(size_t)(k0 + 6) * 64 + n] * WSCALE,
                            wraw[(size_t)(k0 + 7) * 64 + n] * WSCALE, hi);
            return ((ull)hi << 32) | (ull)lo;
        }
    };
    auto step = [&](int kc, ull bb) {
        ull a0 = *(const ull*)(ap0 + kc * 16);
        acc0 = mfma16(bb, a0, acc0);           // swapped: weights = src0
        ull a1 = *(const ull*)(ap1 + kc * 16);
        acc1 = mfma16(bb, a1, acc1);
    };

    ull b0 = loadB(0), b1 = loadB(1), b2 = loadB(2), b3 = loadB(3);
    int kc = 0;
#pragma unroll 1
    for (; kc + 3 < KC; kc += 4) {
        step(kc + 0, b0); b0 = loadB(kc + 4);
        step(kc + 1, b1); b1 = loadB(kc + 5);
        step(kc + 2, b2); b2 = loadB(kc + 6);
        step(kc + 3, b3); b3 = loadB(kc + 7);
    }

    // C^T epilogue: m = row (lane-held batch row), n = ntb*16 + quad*4 + r
    float4 bv = *(const float4*)(bias + ntb * 16 + quad * 4);
    float4 o0, o1;
    o0.x = fmaf(acc0[0], WSCALE_INV, bv.x);
    o0.y = fmaf(acc0[1], WSCALE_INV, bv.y);
    o0.z = fmaf(acc0[2], WSCALE_INV, bv.z);
    o0.w = fmaf(acc0[3], WSCALE_INV, bv.w);
    *(float4*)(Pbuf + row0 * PST + ntb * 16 + quad * 4) = o0;
    o1.x = fmaf(acc1[0], WSCALE_INV, bv.x);
    o1.y = fmaf(acc1[1], WSCALE_INV, bv.y);
    o1.z = fmaf(acc1[2], WSCALE_INV, bv.z);
    o1.w = fmaf(acc1[3], WSCALE_INV, bv.w);
    *(float4*)(Pbuf + row1 * PST + ntb * 16 + quad * 4) = o1;
}

template<bool PACKED>
__global__ __launch_bounds__(512, 2) void flow_kernel(
    const float* __restrict__ inputs,
    const float* __restrict__ ctx,
    const float* __restrict__ W_in,  const float* __restrict__ b_in,
    const float* __restrict__ W_h,   const float* __restrict__ b_h,
    const float* __restrict__ W_out, const float* __restrict__ b_out,
    const int*   __restrict__ perms,
    const uchar* __restrict__ wpk,
    float* __restrict__ out)
{
    __shared__ __align__(16) uchar hbuf0[64 * RS];   // 33,792 B
    __shared__ __align__(16) uchar hbuf1[64 * RS];   // 33,792 B
    __shared__ __align__(16) uchar abuf[64 * AST];   // 13,312 B
    __shared__ __align__(16) float xbuf[64 * NF];    // 16,384 B
    __shared__ int permsh[NF];                        // total 97,536 B

    float* pbuf    = (float*)hbuf1;   // p after G3 (G3 reads hbuf0)
    float* scratch = (float*)hbuf0;   // perm scratch (dead after G3)

    const int tid  = threadIdx.x;     // 0..511
    const int wave = tid >> 6;        // 0..7
    const int lane = tid & 63;
    const int trow = tid >> 3;        // 0..63 (one row per 8 threads)
    const int t8   = tid & 7;         // 0..7
    const int row0 = blockIdx.x * 64;

    // ---- load + clip x tile (2 float4 per thread)
    {
#pragma unroll
        for (int j = 0; j < 2; ++j) {
            float4 v = ((const float4*)(inputs + (size_t)row0 * NF))[tid + j * 512];
            v.x = fminf(fmaxf(v.x, -1.f), 1.f);
            v.y = fminf(fmaxf(v.y, -1.f), 1.f);
            v.z = fminf(fmaxf(v.z, -1.f), 1.f);
            v.w = fminf(fmaxf(v.w, -1.f), 1.f);
            ((float4*)xbuf)[tid + j * 512] = v;
        }
    }
    // ---- stage ctx ONCE into abuf cols 32..159 (split-half layout)
    // thread: row trow, 16 cols from c0 = 32 + t8*16 (8 -> half0, 8 -> half1)
    {
        const float* crow = ctx + (size_t)(row0 + trow) * NCTX + t8 * 16;
        float4 f0 = ((const float4*)crow)[0];
        float4 f1 = ((const float4*)crow)[1];
        float4 f2 = ((const float4*)crow)[2];
        float4 f3 = ((const float4*)crow)[3];
        uint2 ck0, ck1;
        ck0.x = pk2<false>(f0.x, f0.y, 0u);
        ck0.x = pk2<true >(f0.z, f0.w, ck0.x);
        ck0.y = pk2<false>(f1.x, f1.y, 0u);
        ck0.y = pk2<true >(f1.z, f1.w, ck0.y);
        ck1.x = pk2<false>(f2.x, f2.y, 0u);
        ck1.x = pk2<true >(f2.z, f2.w, ck1.x);
        ck1.y = pk2<false>(f3.x, f3.y, 0u);
        ck1.y = pk2<true >(f3.z, f3.w, ck1.y);
        // cols c0..c0+7: half0, pos (2+t8)*8; cols c0+8..c0+15: half1, same pos
        *(uint2*)(abuf + trow * AST + (2 + t8) * 8) = ck0;
        *(uint2*)(abuf + trow * AST + AHALF + (2 + t8) * 8) = ck1;
    }
    // ---- zero-pad abuf cols 160..191 ONCE (A-side of the K=192 pad)
    if (tid < 256) {
        int r = tid >> 2, q = tid & 3;
        *(ull*)(abuf + r * AST + (q & 1) * AHALF + 80 + ((q >> 1) << 3)) = 0ULL;
    }
    float ld_acc = 0.f;
    __syncthreads();

#pragma unroll 1
    for (int i = 0; i < NL; ++i) {
        const int par = i & 1;
        const int idp = par ^ 1;

        // ---- stage id cols 0..31 into abuf (split-half)
        if (t8 < 4) {
            const float* xr = xbuf + trow * NF + idp;
            uint2 idv;
            idv.x = pk2<false>(xr[2 * (t8 * 8 + 0)], xr[2 * (t8 * 8 + 1)], 0u);
            idv.x = pk2<true >(xr[2 * (t8 * 8 + 2)], xr[2 * (t8 * 8 + 3)], idv.x);
            idv.y = pk2<false>(xr[2 * (t8 * 8 + 4)], xr[2 * (t8 * 8 + 5)], 0u);
            idv.y = pk2<true >(xr[2 * (t8 * 8 + 6)], xr[2 * (t8 * 8 + 7)], idv.y);
            // col c = t8*8+j: half = t8&1, pos = (t8>>1)*8 + j
            *(uint2*)(abuf + trow * AST + (t8 & 1) * AHALF + ((t8 >> 1) << 3)) = idv;
        }
        __syncthreads();

        if constexpr (PACKED) {
            // ---- G0: K=192 (padded), 3 K-blocks (abuf -> hbuf0)
            gemm32mx<3>(wpk + OFF_WIN + (size_t)i * WIN_EPL, b_in + i * 512,
                        abuf, AST, AHALF, hbuf0, wave, lane);
            __syncthreads();
            // ---- G1 (hbuf0 -> hbuf1), 8 K-blocks
            gemm32mx<8>(wpk + OFF_WH + (size_t)(i * 2 + 0) * WH_EPB,
                        b_h + (i * 2 + 0) * 512,
                        hbuf0, RS, HHALF, hbuf1, wave, lane);
            __syncthreads();
            // ---- G2 (hbuf1 -> hbuf0)
            gemm32mx<8>(wpk + OFF_WH + (size_t)(i * 2 + 1) * WH_EPB,
                        b_h + (i * 2 + 1) * 512,
                        hbuf1, RS, HHALF, hbuf0, wave, lane);
            __syncthreads();
        } else {
            gemm32_raw<10>(W_in + (size_t)i * (160 * 512), b_in + i * 512,
                           abuf, AST, AHALF, hbuf0, wave * 2 + 0, lane);
            gemm32_raw<10>(W_in + (size_t)i * (160 * 512), b_in + i * 512,
                           abuf, AST, AHALF, hbuf0, wave * 2 + 1, lane);
            __syncthreads();
            gemm32_raw<32>(W_h + (size_t)(i * 2 + 0) * WH_EPB,
                           b_h + (i * 2 + 0) * 512,
                           hbuf0, RS, HHALF, hbuf1, wave * 2 + 0, lane);
            gemm32_raw<32>(W_h + (size_t)(i * 2 + 0) * WH_EPB,
                           b_h + (i * 2 + 0) * 512,
                           hbuf0, RS, HHALF, hbuf1, wave * 2 + 1, lane);
            __syncthreads();
            gemm32_raw<32>(W_h + (size_t)(i * 2 + 1) * WH_EPB,
                           b_h + (i * 2 + 1) * 512,
                           hbuf1, RS, HHALF, hbuf0, wave * 2 + 0, lane);
            gemm32_raw<32>(W_h + (size_t)(i * 2 + 1) * WH_EPB,
                           b_h + (i * 2 + 1) * 512,
                           hbuf1, RS, HHALF, hbuf0, wave * 2 + 1, lane);
            __syncthreads();
        }
        // ---- G3: p = h @ W_out + b_out (hbuf0 -> pbuf = hbuf1)
        gemm16_out<PACKED>(
            PACKED ? wpk + OFF_WOUT + (size_t)i * WOUT_EPL : (const uchar*)0,
            W_out + (size_t)i * WOUT_EPL, b_out + i * 64,
            hbuf0, pbuf, wave, lane);
        __syncthreads();

        // ---- coupling: shift = p[:, :32]; scale = sigmoid(p[:,32:]+2)+1e-3
        {
#pragma unroll
            for (int j = 0; j < 4; ++j) {
                int sc = t8 * 4 + j;
                float shiftv = pbuf[trow * PST + sc];
                float z = pbuf[trow * PST + 32 + sc] + 2.0f;
                float s = 1.0f / (1.0f + __expf(-z)) + 0.001f;
                int tc = 2 * sc + par;
                xbuf[trow * NF + tc] = xbuf[trow * NF + tc] * s + shiftv;
                ld_acc += __logf(s);
            }
        }
        __syncthreads();

        // ---- permutation: x = x[:, perm[i]]  (scratch = hbuf0, dead)
        if (i < NL - 1) {
            ((float4*)scratch)[tid]       = ((float4*)xbuf)[tid];
            ((float4*)scratch)[tid + 512] = ((float4*)xbuf)[tid + 512];
            if (tid < NF) permsh[tid] = perms[i * NF + tid];
            __syncthreads();
#pragma unroll
            for (int j = 0; j < 8; ++j) {
                int c = t8 * 8 + j;
                xbuf[trow * NF + c] = scratch[trow * NF + permsh[c]];
            }
            __syncthreads();
        }
    }

    // ---- outputs: clip(x) then logdet
    {
#pragma unroll
        for (int j = 0; j < 2; ++j) {
            float4 v = ((float4*)xbuf)[tid + j * 512];
            v.x = fminf(fmaxf(v.x, -1.f), 1.f);
            v.y = fminf(fmaxf(v.y, -1.f), 1.f);
            v.z = fminf(fmaxf(v.z, -1.f), 1.f);
            v.w = fminf(fmaxf(v.w, -1.f), 1.f);
            ((float4*)(out + (size_t)row0 * NF))[tid + j * 512] = v;
        }
    }
    // reduce 8 partials per row (lanes 8r..8r+7 contiguous in a wave)
    ld_acc += __shfl_down(ld_acc, 1);
    ld_acc += __shfl_down(ld_acc, 2);
    ld_acc += __shfl_down(ld_acc, 4);
    if (t8 == 0) out[(size_t)BATCH * NF + row0 + trow] = ld_acc;
}

extern "C" void kernel_launch(void* const* d_in, const int* in_sizes, int n_in,
                              void* d_out, int out_size, void* d_ws, size_t ws_size,
                              hipStream_t stream) {
    const float* inputs  = (const float*)d_in[0];
    const float* context = (const float*)d_in[1];
    const float* W_in    = (const float*)d_in[2];
    const float* b_in    = (const float*)d_in[3];
    const float* W_h     = (const float*)d_in[4];
    const float* b_h     = (const float*)d_in[5];
    const float* W_out   = (const float*)d_in[6];
    const float* b_out   = (const float*)d_in[7];
    const int*   perms   = (const int*)d_in[8];
    float* out = (float*)d_out;

    if (ws_size >= (size_t)NEED_WS) {
        uchar* ws = (uchar*)d_ws;
        const int total_threads = (int)(TOT_PACK_ELEMS / 8);    // 655360
        pack_weights_kernel<<<(total_threads + 255) / 256, 256, 0, stream>>>(
            W_in, W_h, W_out, ws);
        flow_kernel<true><<<256, 512, 0, stream>>>(
            inputs, context, W_in, b_in, W_h, b_h, W_out, b_out, perms, ws, out);
    } else {
        flow_kernel<false><<<256, 512, 0, stream>>>(
            inputs, context, W_in, b_in, W_h, b_h, W_out, b_out, perms,
            (const uchar*)0, out);
    }
}

// Round 5
// 198.902 us; speedup vs baseline: 1.4038x; 1.0068x over previous
//
#include <hip/hip_runtime.h>

// ---------------------------------------------------------------------------
// MaskedAutoregressiveFlow (RealNVP coupling) fused kernel for gfx950. R18.
// B=16384 rows, F=64, CTX=128, HID=512, L=8 layers, NB=2 hidden blocks.
//
// R18 = R17 (130us dispatch: MX 32x32x64 fp8 8-wave GEMM cores) with the
//       serial phase scaffolding removed:
//  (a) composed permutations: x stays physically un-permuted; per-layer
//      column map C_i = P_0 o ... o P_{i-1} in LDS (computed once/block).
//      Deletes the perm phase (copy + gather + 2 barriers per layer).
//  (b) coupling fused into G3's epilogue: wave owns ntb {npair, npair+2} x
//      one 16-row m-tile, so each thread holds p[row,sc] AND p[row,32+sc]
//      in registers -> sigmoid/shift/x-update/logdet in-register, direct
//      xbuf write. Deletes pbuf roundtrip + coupling phase + 1 barrier.
//      G3 A-reads halve (one ds_read_b64 feeds both MFMA chains).
//  (c) logdet: per-thread accumulator, one LDS reduce at kernel end.
// Barriers/layer: 8 -> 5. GEMM cores and all MFMA math bit-identical.
// R17 post-mortem: R16(16w,2x LDS traffic)==R17(8w,min traffic)==130us ->
// pacer is the phase scaffolding, not the GEMM inner loops. MfmaUtil is
// work/time by construction (28% == 3.6x MFMA floor), not a stall locator.
// C^T mapping (m101, dtype-indep): 32x32: m = lane&31,
// n = (reg&3)+8*(reg>>2)+4*(lane>>5); 16x16: m = lane&15, n = ntb*16+quad*4+reg.
// LDS h layout: addr(row,c) = row*528 + ((c>>3)&1)*256 + (c>>4)*8 + (c&7).
// ---------------------------------------------------------------------------

typedef float v4f  __attribute__((ext_vector_type(4)));
typedef float v16f __attribute__((ext_vector_type(16)));
typedef int   v4i  __attribute__((ext_vector_type(4)));
typedef int   v8i  __attribute__((ext_vector_type(8)));
typedef unsigned char uchar;
typedef unsigned long long ull;

#define BATCH 16384
#define NF    64
#define NCTX  128
#define NL    8

#define RS     528   // h row stride (bytes)
#define HHALF  256   // byte offset of k-odd 8-byte half groups (hbuf)
#define AST    208   // abuf row stride (bytes), K padded to 192
#define AHALF  96    // abuf half offset (K=192)

#define WSCALE     16.0f
#define WSCALE_INV 0.0625f

// packed-weight offsets (fp8 elements = bytes). W_in K padded 160->192.
#define WIN_EPL   (192 * 512)
#define WH_EPB    (512 * 512)
#define WOUT_EPL  (512 * 64)
#define OFF_WIN   ((size_t)0)
#define OFF_WH    ((size_t)(8 * WIN_EPL))
#define OFF_WOUT  (OFF_WH + (size_t)(16 * WH_EPB))
#define TOT_PACK_ELEMS (OFF_WOUT + (size_t)(8 * WOUT_EPL))
#define NEED_WS   (TOT_PACK_ELEMS)

template<bool HI>
__device__ __forceinline__ unsigned int pk2(float a, float b, unsigned int old) {
    return __builtin_amdgcn_cvt_pk_fp8_f32(a, b, old, HI);
}
__device__ __forceinline__ uchar q8(float v) {
    return (uchar)(__builtin_amdgcn_cvt_pk_fp8_f32(v, v, 0u, false) & 0xffu);
}

// ---------------------------------------------------------------------------
// pack: fp32 -> fp8 e4m3 (x16), DESTINATION-ordered (one 8B store/thread).
// W_in/W_h -> MX 32x32x64 weight-frag order with split-half k-permutation:
//   region kb (32768B) : slot s = strip*64+lane (32B) : group g (8B)
//   lane l: n = strip*32 + (l&31); byte (g*8+j) holds
//   k = kb*64 + (l>>5)*32 + pi[g]*8 + j, pi = {0,2,1,3}. Zero for k>=rawK.
// W_out -> 16x16x32 weight-frag order: frag = kc*4 + nt;
//   lane l: k = kc*32 + (l>>4)*8 + j, n = nt*16 + (l&15).
// ---------------------------------------------------------------------------
__global__ void pack_weights_kernel(const float* __restrict__ W_in,
                                    const float* __restrict__ W_h,
                                    const float* __restrict__ W_out,
                                    unsigned char* __restrict__ ws) {
    const int TIN  = 8 * (WIN_EPL / 8);    //  98304
    const int TH   = 16 * (WH_EPB / 8);    // 524288
    const int TOUT = 8 * (WOUT_EPL / 8);   //  32768
    int t = blockIdx.x * blockDim.x + threadIdx.x;
    if (t >= TIN + TH + TOUT) return;
    float v[8];
    if (t < TIN + TH) {
        const float* src; int r, rawK;
        if (t < TIN) {
            int i = t / (WIN_EPL / 8); r = t - i * (WIN_EPL / 8);
            src = W_in + (size_t)i * (160 * 512); rawK = 160;
        } else {
            int u = t - TIN; int ij = u >> 15; r = u & 32767;
            src = W_h + (size_t)ij * WH_EPB; rawK = 512;
        }
        int kb  = r >> 12, rem = r & 4095;
        int ls  = rem >> 2, g = rem & 3;
        int lane = ls & 63;
        int n = (ls >> 6) * 32 + (lane & 31);
        int pig = (g == 1) ? 2 : (g == 2) ? 1 : g;     // {0,2,1,3}
        int k0 = kb * 64 + (lane >> 5) * 32 + pig * 8;
#pragma unroll
        for (int j = 0; j < 8; ++j) {
            int k = k0 + j;
            v[j] = (k < rawK) ? src[(size_t)k * 512 + n] * WSCALE : 0.f;
        }
    } else {
        int u = t - TIN - TH;
        int i = u >> 12, r = u & 4095;
        const float* src = W_out + (size_t)i * WOUT_EPL;
        int frag = r >> 6, lane = r & 63;
        int k0 = (frag >> 2) * 32 + (lane >> 4) * 8;
        int n  = (frag & 3) * 16 + (lane & 15);
#pragma unroll
        for (int j = 0; j < 8; ++j)
            v[j] = src[(size_t)(k0 + j) * 64 + n] * WSCALE;
    }
    uint2 o;
    o.x = pk2<false>(v[0], v[1], 0u);
    o.x = pk2<true >(v[2], v[3], o.x);
    o.y = pk2<false>(v[4], v[5], 0u);
    o.y = pk2<true >(v[6], v[7], o.y);
    *(uint2*)(ws + (size_t)t * 8) = o;
}

__device__ __forceinline__ v16f mfma32(ull a, ull b, v16f c) {
    return __builtin_amdgcn_mfma_f32_32x32x16_fp8_fp8((long)a, (long)b, c, 0, 0, 0);
}
__device__ __forceinline__ v4f mfma16(ull a, ull b, v4f c) {
    return __builtin_amdgcn_mfma_f32_16x16x32_fp8_fp8((long)a, (long)b, c, 0, 0, 0);
}
// MX K=64, both operands fp8 e4m3 (cbsz=0, blgp=0), scale = 1.0 (E8M0 127).
__device__ __forceinline__ v16f mfma64(v8i a, v8i b, v16f c) {
    return __builtin_amdgcn_mfma_scale_f32_32x32x64_f8f6f4(
        a, b, c, 0, 0, 0, 0x7f7f7f7f, 0, 0x7f7f7f7f);
}

// ---------------------------------------------------------------------------
// MX 32x32x64 fp8 stage, 8-wave: wave owns strips {2p, 2p+1} x both m-tiles
// (4 v16f accs). SWAPPED operands (src0 = weight frag, src1 = act frag).
// Unchanged from R17 (verified core).
// ---------------------------------------------------------------------------
template<int NKB>
__device__ __forceinline__ void gemm32mx(
    const uchar* __restrict__ wpk,
    const float* __restrict__ bias,
    const uchar* __restrict__ Abuf, int ast, int halfoff,
    uchar* __restrict__ Obuf,
    int pair, int lane)
{
    const int l31 = lane & 31, hl = lane >> 5;
    v16f a00, a01, a10, a11;          // acc[strip][mhalf]
#pragma unroll
    for (int r = 0; r < 16; ++r) { a00[r] = 0.f; a01[r] = 0.f;
                                   a10[r] = 0.f; a11[r] = 0.f; }
    const uchar* aLo0 = Abuf + l31 * ast + hl * 16;   // rows 0..31, low region
    const uchar* aHi0 = aLo0 + halfoff;               // high region
    const uchar* aLo1 = aLo0 + 32 * ast;              // rows 32..63
    const uchar* aHi1 = aHi0 + 32 * ast;
    const uchar* bp = wpk + (size_t)(pair * 128 + lane) * 32;  // strip 2p base

    auto loadB = [&](int s, int kb) -> v8i {
        if (kb >= NKB) kb = NKB - 1;                  // clamped dup, in-bounds
        const uchar* p = bp + s * 2048 + (size_t)kb * 32768;
        v4i lo = *(const v4i*)p;
        v4i hi = *(const v4i*)(p + 16);
        return __builtin_shufflevector(lo, hi, 0, 1, 2, 3, 4, 5, 6, 7);
    };
    auto loadA = [&](const uchar* lo_, const uchar* hi_, int kb) -> v8i {
        v4i lo = *(const v4i*)(lo_ + kb * 32);
        v4i hi = *(const v4i*)(hi_ + kb * 32);
        return __builtin_shufflevector(lo, hi, 0, 1, 2, 3, 4, 5, 6, 7);
    };

    v8i b00 = loadB(0, 0), b10 = loadB(1, 0);         // strips, kb
    v8i b01 = loadB(0, 1), b11 = loadB(1, 1);         // strips, kb+1
    int kb = 0;
#pragma unroll 1
    for (; kb + 1 < NKB; kb += 2) {
        v8i x0 = loadA(aLo0, aHi0, kb);
        v8i x1 = loadA(aLo1, aHi1, kb);
        a00 = mfma64(b00, x0, a00);
        a01 = mfma64(b00, x1, a01);
        a10 = mfma64(b10, x0, a10);
        a11 = mfma64(b10, x1, a11);
        b00 = loadB(0, kb + 2); b10 = loadB(1, kb + 2);
        x0 = loadA(aLo0, aHi0, kb + 1);
        x1 = loadA(aLo1, aHi1, kb + 1);
        a00 = mfma64(b01, x0, a00);
        a01 = mfma64(b01, x1, a01);
        a10 = mfma64(b11, x0, a10);
        a11 = mfma64(b11, x1, a11);
        b01 = loadB(0, kb + 3); b11 = loadB(1, kb + 3);
    }
    if constexpr (NKB & 1) {                          // tail kb = NKB-1
        v8i x0 = loadA(aLo0, aHi0, NKB - 1);
        v8i x1 = loadA(aLo1, aHi1, NKB - 1);
        a00 = mfma64(b00, x0, a00);
        a01 = mfma64(b00, x1, a01);
        a10 = mfma64(b10, x0, a10);
        a11 = mfma64(b10, x1, a11);
    }

    // epilogue (C^T): lane = batch row m = l31 (mhalf0) / l31+32 (mhalf1);
    // reg-quad q of strip s covers n = s*32 + q*8 + 4*hl + {0..3}.
    const uchar* ob0 = Obuf + l31 * RS + 4 * hl;      // mhalf 0
    const uchar* ob1 = ob0 + 32 * RS;                 // mhalf 1
    auto emit = [&](const v16f& am0, const v16f& am1, int strip) {
#pragma unroll
        for (int q = 0; q < 4; ++q) {
            const int n0 = strip * 32 + q * 8 + 4 * hl;
            float4 bv = *(const float4*)(bias + n0);
            unsigned int u0, u1;
            u0 = pk2<false>(fmaxf(fmaf(am0[4 * q + 0], WSCALE_INV, bv.x), 0.f),
                            fmaxf(fmaf(am0[4 * q + 1], WSCALE_INV, bv.y), 0.f), 0u);
            u0 = pk2<true >(fmaxf(fmaf(am0[4 * q + 2], WSCALE_INV, bv.z), 0.f),
                            fmaxf(fmaf(am0[4 * q + 3], WSCALE_INV, bv.w), 0.f), u0);
            u1 = pk2<false>(fmaxf(fmaf(am1[4 * q + 0], WSCALE_INV, bv.x), 0.f),
                            fmaxf(fmaf(am1[4 * q + 1], WSCALE_INV, bv.y), 0.f), 0u);
            u1 = pk2<true >(fmaxf(fmaf(am1[4 * q + 2], WSCALE_INV, bv.z), 0.f),
                            fmaxf(fmaf(am1[4 * q + 3], WSCALE_INV, bv.w), 0.f), u1);
            const int g = strip * 4 + q;              // 8-col group index
            const int off = (g & 1) * HHALF + ((g >> 1) << 3);
            *(unsigned int*)(ob0 + off) = u0;
            *(unsigned int*)(ob1 + off) = u1;
        }
    };
    emit(a00, a01, pair * 2 + 0);
    emit(a10, a11, pair * 2 + 1);
}

// ---------------------------------------------------------------------------
// Non-packed fallback: 32x32x16 fp8 stage (pk on the fly, original operand
// order + byte epilogue — correctness path only).
// ---------------------------------------------------------------------------
template<int KC>
__device__ __forceinline__ void gemm32_raw(
    const float* __restrict__ wraw,    // raw fp32 [K][512]
    const float* __restrict__ bias,
    const uchar* __restrict__ Abuf, int ast, int ahalf,
    uchar* __restrict__ Obuf,
    int strip, int lane)
{
    constexpr int P = KC / 2;
    const int l31 = lane & 31, hl = lane >> 5;
    v16f acc0, acc1;
#pragma unroll
    for (int r = 0; r < 16; ++r) { acc0[r] = 0.f; acc1[r] = 0.f; }
    const uchar* a0p = Abuf + l31 * ast + hl * ahalf;   // rows 0..31
    const uchar* a1p = a0p + 32 * ast;                  // rows 32..63

    auto loadB = [&](int kc) -> ull {
        if (kc >= KC) kc = KC - 1;
        int n  = strip * 32 + l31;
        int k0 = kc * 16 + hl * 8;
        unsigned int lo, hi;
        lo = pk2<false>(wraw[(size_t)(k0 + 0) * 512 + n] * WSCALE,
                        wraw[(size_t)(k0 + 1) * 512 + n] * WSCALE, 0u);
        lo = pk2<true >(wraw[(size_t)(k0 + 2) * 512 + n] * WSCALE,
                        wraw[(size_t)(k0 + 3) * 512 + n] * WSCALE, lo);
        hi = pk2<false>(wraw[(size_t)(k0 + 4) * 512 + n] * WSCALE,
                        wraw[(size_t)(k0 + 5) * 512 + n] * WSCALE, 0u);
        hi = pk2<true >(wraw[(size_t)(k0 + 6) * 512 + n] * WSCALE,
                        wraw[(size_t)(k0 + 7) * 512 + n] * WSCALE, hi);
        return ((ull)hi << 32) | (ull)lo;
    };

    ull b0 = loadB(0), b1 = loadB(1), b2 = loadB(2), b3 = loadB(3);
    int p2 = 0;
#pragma unroll 1
    for (; p2 + 1 < P; p2 += 2) {
        ulonglong2 Aa0 = *(const ulonglong2*)(a0p + p2 * 16);
        ulonglong2 Aa1 = *(const ulonglong2*)(a1p + p2 * 16);
        acc0 = mfma32(Aa0.x, b0, acc0);
        acc1 = mfma32(Aa1.x, b0, acc1);
        b0 = loadB(2 * p2 + 4);
        acc0 = mfma32(Aa0.y, b1, acc0);
        acc1 = mfma32(Aa1.y, b1, acc1);
        b1 = loadB(2 * p2 + 5);
        ulonglong2 Ab0 = *(const ulonglong2*)(a0p + p2 * 16 + 16);
        ulonglong2 Ab1 = *(const ulonglong2*)(a1p + p2 * 16 + 16);
        acc0 = mfma32(Ab0.x, b2, acc0);
        acc1 = mfma32(Ab1.x, b2, acc1);
        b2 = loadB(2 * p2 + 6);
        acc0 = mfma32(Ab0.y, b3, acc0);
        acc1 = mfma32(Ab1.y, b3, acc1);
        b3 = loadB(2 * p2 + 7);
    }
    if constexpr (P & 1) {
        ulonglong2 Aa0 = *(const ulonglong2*)(a0p + (P - 1) * 16);
        ulonglong2 Aa1 = *(const ulonglong2*)(a1p + (P - 1) * 16);
        acc0 = mfma32(Aa0.x, b0, acc0);
        acc1 = mfma32(Aa1.x, b0, acc1);
        acc0 = mfma32(Aa0.y, b1, acc0);
        acc1 = mfma32(Aa1.y, b1, acc1);
    }

    const int n = strip * 32 + l31;
    const int nb = ((n >> 3) & 1) * HHALF + ((n >> 4) << 3) + (n & 7);
    const float bv = bias[n];
#pragma unroll
    for (int reg = 0; reg < 16; ++reg) {
        int row = (reg & 3) + 8 * (reg >> 2) + 4 * hl;
        float v0 = fmaxf(fmaf(acc0[reg], WSCALE_INV, bv), 0.f);
        Obuf[row * RS + nb] = q8(v0);
        float v1 = fmaxf(fmaf(acc1[reg], WSCALE_INV, bv), 0.f);
        Obuf[(row + 32) * RS + nb] = q8(v1);
    }
}

// ---------------------------------------------------------------------------
// G3 + coupling, fused (16x16x32 fp8, SWAPPED: src0 = W_out frag).
// wave w: mtb = w>>1 (16-row m-tile), npair = w&1; chains ntb0 = npair
// (p shift cols sc = npair*16+quad*4+r) and ntb1 = npair+2 (p scale cols
// 32+sc). One ds_read_b64 per kc feeds BOTH chains. Epilogue computes
// sigmoid/shift in-register and updates xbuf[row, C_i[2*sc+par]] directly;
// returns the thread's logdet partial for this layer.
// Thread <-> (row = mtb*16 + l15, slot = npair*4 + quad) is bijective.
// ---------------------------------------------------------------------------
template<bool PACKED>
__device__ __forceinline__ float gemm16_fused(
    const uchar* __restrict__ wpk,
    const float* __restrict__ wraw,    // raw fp32 W_out [512][64]
    const float* __restrict__ bias,
    const uchar* __restrict__ Abuf,
    float* __restrict__ xbuf,
    const int* __restrict__ ct,        // Ctab row for this layer (64 ints)
    int par, int w, int lane)
{
    const int quad = lane >> 4, l15 = lane & 15;
    const int mtb  = w >> 1;           // 0..3
    const int npair = w & 1;
    const int ntb0 = npair, ntb1 = npair + 2;
    const int row  = mtb * 16 + l15;
    v4f acc0, acc1;
    acc0[0] = acc0[1] = acc0[2] = acc0[3] = 0.f;
    acc1[0] = acc1[1] = acc1[2] = acc1[3] = 0.f;
    // c = kc*32 + quad*8 + j -> half = quad&1, pos = (kc*2 + (quad>>1))*8 + j
    const uchar* ap = Abuf + row * RS + (quad & 1) * HHALF + ((quad >> 1) << 3);
    const uchar* bp0 =
        PACKED ? wpk + (size_t)(ntb0 * 64 + lane) * 8 : (const uchar*)0;
    const uchar* bp1 =
        PACKED ? wpk + (size_t)(ntb1 * 64 + lane) * 8 : (const uchar*)0;
    constexpr int KC = 16;

    auto loadB = [&](const uchar* bp, int ntb, int kc) -> ull {
        if (kc >= KC) kc = KC - 1;
        if constexpr (PACKED) {
            return *(const ull*)(bp + (size_t)kc * 2048);   // 4 frags x 512B
        } else {
            int n  = ntb * 16 + l15;
            int k0 = kc * 32 + quad * 8;
            unsigned int lo, hi;
            lo = pk2<false>(wraw[(size_t)(k0 + 0) * 64 + n] * WSCALE,
                            wraw[(size_t)(k0 + 1) * 64 + n] * WSCALE, 0u);
            lo = pk2<true >(wraw[(size_t)(k0 + 2) * 64 + n] * WSCALE,
                            wraw[(size_t)(k0 + 3) * 64 + n] * WSCALE, lo);
            hi = pk2<false>(wraw[(size_t)(k0 + 4) * 64 + n] * WSCALE,
                            wraw[(size_t)(k0 + 5) * 64 + n] * WSCALE, 0u);
            hi = pk2<true >(wraw[(size_t)(k0 + 6) * 64 + n] * WSCALE,
                            wraw[(size_t)(k0 + 7) * 64 + n] * WSCALE, hi);
            return ((ull)hi << 32) | (ull)lo;
        }
    };
    auto step = [&](int kc, ull bu, ull bv_) {
        ull a = *(const ull*)(ap + kc * 16);
        acc0 = mfma16(bu, a, acc0);            // swapped: weights = src0
        acc1 = mfma16(bv_, a, acc1);
    };

    ull u0 = loadB(bp0, ntb0, 0), u1 = loadB(bp0, ntb0, 1);
    ull u2 = loadB(bp0, ntb0, 2), u3 = loadB(bp0, ntb0, 3);
    ull v0 = loadB(bp1, ntb1, 0), v1 = loadB(bp1, ntb1, 1);
    ull v2 = loadB(bp1, ntb1, 2), v3 = loadB(bp1, ntb1, 3);
    int kc = 0;
#pragma unroll 1
    for (; kc + 3 < KC; kc += 4) {
        step(kc + 0, u0, v0);
        u0 = loadB(bp0, ntb0, kc + 4); v0 = loadB(bp1, ntb1, kc + 4);
        step(kc + 1, u1, v1);
        u1 = loadB(bp0, ntb0, kc + 5); v1 = loadB(bp1, ntb1, kc + 5);
        step(kc + 2, u2, v2);
        u2 = loadB(bp0, ntb0, kc + 6); v2 = loadB(bp1, ntb1, kc + 6);
        step(kc + 3, u3, v3);
        u3 = loadB(bp0, ntb0, kc + 7); v3 = loadB(bp1, ntb1, kc + 7);
    }

    // fused coupling epilogue: sc = npair*16 + quad*4 + r (bijective over
    // 0..31 per row across the wave's threads).
    const int n0 = ntb0 * 16 + quad * 4;
    float ld = 0.f;
#pragma unroll
    for (int r = 0; r < 4; ++r) {
        float shiftv = fmaf(acc0[r], WSCALE_INV, bias[n0 + r]);
        float z      = fmaf(acc1[r], WSCALE_INV, bias[32 + n0 + r]) + 2.0f;
        float s      = 1.0f / (1.0f + __expf(-z)) + 0.001f;
        int sc = n0 + r;
        int tc = ct[2 * sc + par];                  // physical column
        float xo = xbuf[row * NF + tc];
        xbuf[row * NF + tc] = xo * s + shiftv;
        ld += __logf(s);
    }
    return ld;
}

template<bool PACKED>
__global__ __launch_bounds__(512, 2) void flow_kernel(
    const float* __restrict__ inputs,
    const float* __restrict__ ctx,
    const float* __restrict__ W_in,  const float* __restrict__ b_in,
    const float* __restrict__ W_h,   const float* __restrict__ b_h,
    const float* __restrict__ W_out, const float* __restrict__ b_out,
    const int*   __restrict__ perms,
    const uchar* __restrict__ wpk,
    float* __restrict__ out)
{
    __shared__ __align__(16) uchar hbuf0[64 * RS];   // 33,792 B
    __shared__ __align__(16) uchar hbuf1[64 * RS];   // 33,792 B
    __shared__ __align__(16) uchar abuf[64 * AST];   // 13,312 B
    __shared__ __align__(16) float xbuf[64 * NF];    // 16,384 B
    __shared__ int Ctab[NL * NF];                    //  2,048 B (~99.3 KB)

    const int tid  = threadIdx.x;     // 0..511
    const int wave = tid >> 6;        // 0..7
    const int lane = tid & 63;
    const int trow = tid >> 3;        // 0..63 (one row per 8 threads)
    const int t8   = tid & 7;         // 0..7
    const int row0 = blockIdx.x * 64;

    // ---- composed perms: Ctab[i][c] = P_0[P_1[...P_{i-1}[c]]]
    {
        int i = tid >> 6, c = tid & 63;     // tid covers all 8*64 entries
        int idx = c;
        for (int k = i - 1; k >= 0; --k) idx = perms[k * NF + idx];
        Ctab[tid] = idx;
    }
    // ---- load + clip x tile (2 float4 per thread)
    {
#pragma unroll
        for (int j = 0; j < 2; ++j) {
            float4 v = ((const float4*)(inputs + (size_t)row0 * NF))[tid + j * 512];
            v.x = fminf(fmaxf(v.x, -1.f), 1.f);
            v.y = fminf(fmaxf(v.y, -1.f), 1.f);
            v.z = fminf(fmaxf(v.z, -1.f), 1.f);
            v.w = fminf(fmaxf(v.w, -1.f), 1.f);
            ((float4*)xbuf)[tid + j * 512] = v;
        }
    }
    // ---- stage ctx ONCE into abuf cols 32..159 (split-half layout)
    {
        const float* crow = ctx + (size_t)(row0 + trow) * NCTX + t8 * 16;
        float4 f0 = ((const float4*)crow)[0];
        float4 f1 = ((const float4*)crow)[1];
        float4 f2 = ((const float4*)crow)[2];
        float4 f3 = ((const float4*)crow)[3];
        uint2 ck0, ck1;
        ck0.x = pk2<false>(f0.x, f0.y, 0u);
        ck0.x = pk2<true >(f0.z, f0.w, ck0.x);
        ck0.y = pk2<false>(f1.x, f1.y, 0u);
        ck0.y = pk2<true >(f1.z, f1.w, ck0.y);
        ck1.x = pk2<false>(f2.x, f2.y, 0u);
        ck1.x = pk2<true >(f2.z, f2.w, ck1.x);
        ck1.y = pk2<false>(f3.x, f3.y, 0u);
        ck1.y = pk2<true >(f3.z, f3.w, ck1.y);
        // cols c0..c0+7: half0, pos (2+t8)*8; cols c0+8..c0+15: half1, same pos
        *(uint2*)(abuf + trow * AST + (2 + t8) * 8) = ck0;
        *(uint2*)(abuf + trow * AST + AHALF + (2 + t8) * 8) = ck1;
    }
    // ---- zero-pad abuf cols 160..191 ONCE (A-side of the K=192 pad)
    if (tid < 256) {
        int r = tid >> 2, q = tid & 3;
        *(ull*)(abuf + r * AST + (q & 1) * AHALF + 80 + ((q >> 1) << 3)) = 0ULL;
    }
    float ld_acc = 0.f;
    __syncthreads();

#pragma unroll 1
    for (int i = 0; i < NL; ++i) {
        const int par = i & 1;
        const int idp = par ^ 1;
        const int* ct = Ctab + i * NF;

        // ---- stage id cols 0..31 into abuf (split-half) via composed perm
        if (t8 < 4) {
            const float* xr = xbuf + trow * NF;
            uint2 idv;
            idv.x = pk2<false>(xr[ct[2 * (t8 * 8 + 0) + idp]],
                               xr[ct[2 * (t8 * 8 + 1) + idp]], 0u);
            idv.x = pk2<true >(xr[ct[2 * (t8 * 8 + 2) + idp]],
                               xr[ct[2 * (t8 * 8 + 3) + idp]], idv.x);
            idv.y = pk2<false>(xr[ct[2 * (t8 * 8 + 4) + idp]],
                               xr[ct[2 * (t8 * 8 + 5) + idp]], 0u);
            idv.y = pk2<true >(xr[ct[2 * (t8 * 8 + 6) + idp]],
                               xr[ct[2 * (t8 * 8 + 7) + idp]], idv.y);
            // col c = t8*8+j: half = t8&1, pos = (t8>>1)*8 + j
            *(uint2*)(abuf + trow * AST + (t8 & 1) * AHALF + ((t8 >> 1) << 3)) = idv;
        }
        __syncthreads();

        if constexpr (PACKED) {
            // ---- G0: K=192 (padded), 3 K-blocks (abuf -> hbuf0)
            gemm32mx<3>(wpk + OFF_WIN + (size_t)i * WIN_EPL, b_in + i * 512,
                        abuf, AST, AHALF, hbuf0, wave, lane);
            __syncthreads();
            // ---- G1 (hbuf0 -> hbuf1), 8 K-blocks
            gemm32mx<8>(wpk + OFF_WH + (size_t)(i * 2 + 0) * WH_EPB,
                        b_h + (i * 2 + 0) * 512,
                        hbuf0, RS, HHALF, hbuf1, wave, lane);
            __syncthreads();
            // ---- G2 (hbuf1 -> hbuf0)
            gemm32mx<8>(wpk + OFF_WH + (size_t)(i * 2 + 1) * WH_EPB,
                        b_h + (i * 2 + 1) * 512,
                        hbuf1, RS, HHALF, hbuf0, wave, lane);
            __syncthreads();
        } else {
            gemm32_raw<10>(W_in + (size_t)i * (160 * 512), b_in + i * 512,
                           abuf, AST, AHALF, hbuf0, wave * 2 + 0, lane);
            gemm32_raw<10>(W_in + (size_t)i * (160 * 512), b_in + i * 512,
                           abuf, AST, AHALF, hbuf0, wave * 2 + 1, lane);
            __syncthreads();
            gemm32_raw<32>(W_h + (size_t)(i * 2 + 0) * WH_EPB,
                           b_h + (i * 2 + 0) * 512,
                           hbuf0, RS, HHALF, hbuf1, wave * 2 + 0, lane);
            gemm32_raw<32>(W_h + (size_t)(i * 2 + 0) * WH_EPB,
                           b_h + (i * 2 + 0) * 512,
                           hbuf0, RS, HHALF, hbuf1, wave * 2 + 1, lane);
            __syncthreads();
            gemm32_raw<32>(W_h + (size_t)(i * 2 + 1) * WH_EPB,
                           b_h + (i * 2 + 1) * 512,
                           hbuf1, RS, HHALF, hbuf0, wave * 2 + 0, lane);
            gemm32_raw<32>(W_h + (size_t)(i * 2 + 1) * WH_EPB,
                           b_h + (i * 2 + 1) * 512,
                           hbuf1, RS, HHALF, hbuf0, wave * 2 + 1, lane);
            __syncthreads();
        }
        // ---- G3 + coupling fused (hbuf0 -> xbuf update, ld partial)
        ld_acc += gemm16_fused<PACKED>(
            PACKED ? wpk + OFF_WOUT + (size_t)i * WOUT_EPL : (const uchar*)0,
            W_out + (size_t)i * WOUT_EPL, b_out + i * 64,
            hbuf0, xbuf, ct, par, wave, lane);
        __syncthreads();
    }

    // ---- outputs: out[:, c] = clip(x_phys[C_7[c]]) (final gather)
    {
        const int* c7 = Ctab + 7 * NF;
#pragma unroll
        for (int j = 0; j < 2; ++j) {
            int p = tid + j * 512;
            int r = p >> 4, c0 = (p & 15) * 4;
            const float* xr = xbuf + r * NF;
            float4 v;
            v.x = fminf(fmaxf(xr[c7[c0 + 0]], -1.f), 1.f);
            v.y = fminf(fmaxf(xr[c7[c0 + 1]], -1.f), 1.f);
            v.z = fminf(fmaxf(xr[c7[c0 + 2]], -1.f), 1.f);
            v.w = fminf(fmaxf(xr[c7[c0 + 3]], -1.f), 1.f);
            ((float4*)(out + (size_t)row0 * NF))[p] = v;
        }
    }
    // ---- logdet: per-thread partials -> LDS (abuf, dead) -> 8-way reduce
    {
        float* lbuf = (float*)abuf;
        const int rrow = (wave >> 1) * 16 + (lane & 15);
        const int slot = (wave & 1) * 4 + (lane >> 4);
        lbuf[rrow * 8 + slot] = ld_acc;
        __syncthreads();
        if (tid < 64) {
            float s = 0.f;
#pragma unroll
            for (int k = 0; k < 8; ++k) s += lbuf[tid * 8 + k];
            out[(size_t)BATCH * NF + row0 + tid] = s;
        }
    }
}

extern "C" void kernel_launch(void* const* d_in, const int* in_sizes, int n_in,
                              void* d_out, int out_size, void* d_ws, size_t ws_size,
                              hipStream_t stream) {
    const float* inputs  = (const float*)d_in[0];
    const float* context = (const float*)d_in[1];
    const float* W_in    = (const float*)d_in[2];
    const float* b_in    = (const float*)d_in[3];
    const float* W_h     = (const float*)d_in[4];
    const float* b_h     = (const float*)d_in[5];
    const float* W_out   = (const float*)d_in[6];
    const float* b_out   = (const float*)d_in[7];
    const int*   perms   = (const int*)d_in[8];
    float* out = (float*)d_out;

    if (ws_size >= (size_t)NEED_WS) {
        uchar* ws = (uchar*)d_ws;
        const int total_threads = (int)(TOT_PACK_ELEMS / 8);    // 655360
        pack_weights_kernel<<<(total_threads + 255) / 256, 256, 0, stream>>>(
            W_in, W_h, W_out, ws);
        flow_kernel<true><<<256, 512, 0, stream>>>(
            inputs, context, W_in, b_in, W_h, b_h, W_out, b_out, perms, ws, out);
    } else {
        flow_kernel<false><<<256, 512, 0, stream>>>(
            inputs, context, W_in, b_in, W_h, b_h, W_out, b_out, perms,
            (const uchar*)0, out);
    }
}